// Round 11
// baseline (16360.683 us; speedup 1.0000x reference)
//
#include <hip/hip_runtime.h>
#include <hip/hip_bf16.h>
#include <math.h>

#define NN 4096
#define DIN 2048
#define HID 256
#define NHEADS 4
#define CAP 1024       // fast-path nnz per row; multiple of 8 (padding invariant)
#define OVF_CAP 131072 // spill capacity for rows exceeding CAP (exactness guarantee)
#define PW 128         // spmm panel width (floats): 4096*PW*4B = 2MB panel -> fits one XCD L2

// ---------------------------------------------------------------------------
// Projection GEMM (NT): out[n][c] = sum_d X[n][d]*W[c][d] + b[c]
// 64x64 tile, 4x4 per thread. Head-batched: blockIdx.z = head*2 + isK
// (grid z=8, 2048 blocks = 8/CU; round-8 counters: occupancy 5.7->62%).
// ---------------------------------------------------------------------------
__global__ __launch_bounds__(256) void proj_kernel(
    const float* __restrict__ X, const float* __restrict__ Wq, const float* __restrict__ bq,
    const float* __restrict__ Wk, const float* __restrict__ bk,
    float* __restrict__ qb, float* __restrict__ kb, int h0)
{
    const int isK  = blockIdx.z & 1;
    const int hidx = blockIdx.z >> 1;        // head index within this launch
    const int hh   = h0 + hidx;              // weight head
    const float* W    = (isK ? Wk : Wq) + (size_t)hh * HID * DIN;
    const float* bias = (isK ? bk : bq) + hh * HID;
    float* out = (isK ? kb : qb) + (size_t)hidx * NN * HID;

    const int bm = blockIdx.x * 64;
    const int bn = blockIdx.y * 64;
    const int t  = threadIdx.x;
    const int tx = t & 15, ty = t >> 4;
    const int lr = t >> 2, lk = (t & 3) * 4;

    __shared__ float As[16][68];
    __shared__ float Bs[16][68];
    float acc[4][4] = {};

    for (int k0 = 0; k0 < DIN; k0 += 16) {
        float4 av = *(const float4*)(X + (size_t)(bm + lr) * DIN + k0 + lk);
        float4 bv = *(const float4*)(W + (size_t)(bn + lr) * DIN + k0 + lk);
        As[lk+0][lr]=av.x; As[lk+1][lr]=av.y; As[lk+2][lr]=av.z; As[lk+3][lr]=av.w;
        Bs[lk+0][lr]=bv.x; Bs[lk+1][lr]=bv.y; Bs[lk+2][lr]=bv.z; Bs[lk+3][lr]=bv.w;
        __syncthreads();
        #pragma unroll
        for (int kk = 0; kk < 16; ++kk) {
            const float4 a4 = *(const float4*)&As[kk][ty*4];
            const float4 b4 = *(const float4*)&Bs[kk][tx*4];
            const float a[4] = {a4.x,a4.y,a4.z,a4.w};
            const float b[4] = {b4.x,b4.y,b4.z,b4.w};
            #pragma unroll
            for (int i = 0; i < 4; ++i)
                #pragma unroll
                for (int j = 0; j < 4; ++j)
                    acc[i][j] = fmaf(a[i], b[j], acc[i][j]);
        }
        __syncthreads();
    }
    #pragma unroll
    for (int i = 0; i < 4; ++i) {
        const int m = bm + ty*4 + i;
        float4 o;
        o.x = acc[i][0] + bias[bn+tx*4+0];
        o.y = acc[i][1] + bias[bn+tx*4+1];
        o.z = acc[i][2] + bias[bn+tx*4+2];
        o.w = acc[i][3] + bias[bn+tx*4+3];
        *(float4*)(out + (size_t)m * HID + bn + tx*4) = o;
    }
}

// ---------------------------------------------------------------------------
// Row sum-of-squares; head-batched via blockIdx.z (0 in fallback mode).
// ---------------------------------------------------------------------------
__global__ __launch_bounds__(64) void rownorm_kernel(
    const float* __restrict__ q, const float* __restrict__ k,
    float* __restrict__ sqq, float* __restrict__ sqk)
{
    const int row = blockIdx.x;
    const int hz  = blockIdx.z;
    const int lane = threadIdx.x;
    const float* src = (blockIdx.y ? k : q) + ((size_t)hz * NN + row) * HID;
    float4 v = *(const float4*)(src + lane * 4);
    float s = v.x*v.x + v.y*v.y + v.z*v.z + v.w*v.w;
    for (int off = 32; off; off >>= 1) s += __shfl_down(s, off);
    if (lane == 0) (blockIdx.y ? sqk : sqq)[(size_t)hz * NN + row] = s;
}

// ---------------------------------------------------------------------------
// Gram GEMM (NT, K=HID) + distance epilogue. 64x64 proven config.
// ---------------------------------------------------------------------------
__global__ __launch_bounds__(256) void dist_kernel(
    const float* __restrict__ q, const float* __restrict__ k,
    const float* __restrict__ sqq, const float* __restrict__ sqk,
    float* __restrict__ Dm)
{
    const int bm = blockIdx.x * 64;
    const int bn = blockIdx.y * 64;
    const int t  = threadIdx.x;
    const int tx = t & 15, ty = t >> 4;
    const int lr = t >> 2, lk = (t & 3) * 4;

    __shared__ float As[16][68];
    __shared__ float Bs[16][68];
    float acc[4][4] = {};

    for (int k0 = 0; k0 < HID; k0 += 16) {
        float4 av = *(const float4*)(q + (size_t)(bm + lr) * HID + k0 + lk);
        float4 bv = *(const float4*)(k + (size_t)(bn + lr) * HID + k0 + lk);
        As[lk+0][lr]=av.x; As[lk+1][lr]=av.y; As[lk+2][lr]=av.z; As[lk+3][lr]=av.w;
        Bs[lk+0][lr]=bv.x; Bs[lk+1][lr]=bv.y; Bs[lk+2][lr]=bv.z; Bs[lk+3][lr]=bv.w;
        __syncthreads();
        #pragma unroll
        for (int kk = 0; kk < 16; ++kk) {
            const float4 a4 = *(const float4*)&As[kk][ty*4];
            const float4 b4 = *(const float4*)&Bs[kk][tx*4];
            const float a[4] = {a4.x,a4.y,a4.z,a4.w};
            const float b[4] = {b4.x,b4.y,b4.z,b4.w};
            #pragma unroll
            for (int i = 0; i < 4; ++i)
                #pragma unroll
                for (int j = 0; j < 4; ++j)
                    acc[i][j] = fmaf(a[i], b[j], acc[i][j]);
        }
        __syncthreads();
    }
    #pragma unroll
    for (int i = 0; i < 4; ++i) {
        const int m = bm + ty*4 + i;
        const float sm = sqq[m];
        float4 o;
        float v0 = sm + sqk[bn+tx*4+0] - 2.0f*acc[i][0];
        float v1 = sm + sqk[bn+tx*4+1] - 2.0f*acc[i][1];
        float v2 = sm + sqk[bn+tx*4+2] - 2.0f*acc[i][2];
        float v3 = sm + sqk[bn+tx*4+3] - 2.0f*acc[i][3];
        o.x = sqrtf(fmaxf(v0, 0.0f) + 1e-10f);
        o.y = sqrtf(fmaxf(v1, 0.0f) + 1e-10f);
        o.z = sqrtf(fmaxf(v2, 0.0f) + 1e-10f);
        o.w = sqrtf(fmaxf(v3, 0.0f) + 1e-10f);
        *(float4*)(Dm + (size_t)m * NN + bn + tx*4) = o;
    }
}

// ---------------------------------------------------------------------------
// Per-row order stats: 11th and 30th smallest via register-resident radix
// bisection + ballot counting (no LDS; bit-identical ranks).
// ---------------------------------------------------------------------------
__device__ __forceinline__ unsigned kth_reg(const unsigned (&r)[64], int K)
{
    unsigned lo = 0u, hi = 0xFFFFFFFFu;
    while (lo < hi) {
        unsigned mid = lo + ((hi - lo) >> 1);
        int c = 0;
        #pragma unroll
        for (int i = 0; i < 64; ++i)
            c += (int)__popcll(__ballot(r[i] <= mid));
        if (c >= K) hi = mid; else lo = mid + 1;
    }
    return lo;
}

__global__ __launch_bounds__(64) void select_kernel(
    const float* __restrict__ Dm, float* __restrict__ mdp, float* __restrict__ kth)
{
    const int row = blockIdx.x;
    const int lane = threadIdx.x;
    const float* src = Dm + (size_t)row * NN + lane * 64;  // per-lane contiguous 256B
    unsigned r[64];
    #pragma unroll
    for (int c = 0; c < 16; ++c) {
        float4 v = *(const float4*)(src + c * 4);
        r[c*4+0] = __float_as_uint(v.x);
        r[c*4+1] = __float_as_uint(v.y);
        r[c*4+2] = __float_as_uint(v.z);
        r[c*4+3] = __float_as_uint(v.w);
    }
    unsigned v11 = kth_reg(r, 11);   // sort(d)[10]
    unsigned v30 = kth_reg(r, 30);   // sort(d)[29]
    if (lane == 0) {
        float md = __uint_as_float(v11) + 1e-10f;
        float t  = __uint_as_float(v30) / md;
        mdp[row] = md;
        kth[row] = expf(-(t*t));   // same expr as affsym -> identical rounding
    }
}

// ---------------------------------------------------------------------------
// FUSED affinity + symmetrize: A := aff(D) + aff(D)^T in one pass (round 10:
// one 128MB pass and 8 launches eliminated; bit-identical A). Block 0 also
// zeroes ovf_cnt (stream order: affsym completes before stats_extract).
// ---------------------------------------------------------------------------
__device__ __forceinline__ void aff4(float4& v, float m, float kt, bool diagtile,
                                     int r, int lc4)
{
    float t0 = v.x / m, t1 = v.y / m, t2 = v.z / m, t3 = v.w / m;
    float a0 = expf(-(t0*t0)), a1 = expf(-(t1*t1)), a2 = expf(-(t2*t2)), a3 = expf(-(t3*t3));
    a0 = (a0 >= kt) ? a0 : 0.0f;
    a1 = (a1 >= kt) ? a1 : 0.0f;
    a2 = (a2 >= kt) ? a2 : 0.0f;
    a3 = (a3 >= kt) ? a3 : 0.0f;
    if (diagtile) {
        if (lc4+0 == r) a0 = 1.0f;
        if (lc4+1 == r) a1 = 1.0f;
        if (lc4+2 == r) a2 = 1.0f;
        if (lc4+3 == r) a3 = 1.0f;
    }
    v.x = a0; v.y = a1; v.z = a2; v.w = a3;
}

__global__ __launch_bounds__(256) void affsym_kernel(
    float* __restrict__ Dm, const float* __restrict__ mdp, const float* __restrict__ kthv,
    int* __restrict__ ovf_cnt)
{
    if (blockIdx.x == 0 && threadIdx.x == 0) *ovf_cnt = 0;

    int rem = blockIdx.x;
    int bi = 0;
    while (rem >= 64 - bi) { rem -= 64 - bi; ++bi; }
    const int bj = bi + rem;
    const bool diagtile = (bi == bj);

    __shared__ float T1[64][65];
    __shared__ float T2[64][65];
    const int t = threadIdx.x;
    const int lr = t >> 4;
    const int lc4 = (t & 15) * 4;

    #pragma unroll
    for (int rr = 0; rr < 4; ++rr) {
        const int r = rr*16 + lr;
        {
            const int grow = bi*64 + r;
            const float m  = mdp[grow];
            const float kt = kthv[grow];
            float4 v1 = *(const float4*)(Dm + (size_t)grow * NN + bj*64 + lc4);
            aff4(v1, m, kt, diagtile, r, lc4);
            T1[r][lc4+0]=v1.x; T1[r][lc4+1]=v1.y; T1[r][lc4+2]=v1.z; T1[r][lc4+3]=v1.w;
        }
        {
            const int grow = bj*64 + r;
            const float m  = mdp[grow];
            const float kt = kthv[grow];
            float4 v2 = *(const float4*)(Dm + (size_t)grow * NN + bi*64 + lc4);
            aff4(v2, m, kt, diagtile, r, lc4);
            T2[r][lc4+0]=v2.x; T2[r][lc4+1]=v2.y; T2[r][lc4+2]=v2.z; T2[r][lc4+3]=v2.w;
        }
    }
    __syncthreads();
    #pragma unroll
    for (int rr = 0; rr < 4; ++rr) {
        const int r = rr*16 + lr;
        float4 o1;
        o1.x = T1[r][lc4+0] + T2[lc4+0][r];
        o1.y = T1[r][lc4+1] + T2[lc4+1][r];
        o1.z = T1[r][lc4+2] + T2[lc4+2][r];
        o1.w = T1[r][lc4+3] + T2[lc4+3][r];
        *(float4*)(Dm + (size_t)(bi*64 + r) * NN + bj*64 + lc4) = o1;
        if (!diagtile) {
            float4 o2;
            o2.x = T2[r][lc4+0] + T1[lc4+0][r];
            o2.y = T2[r][lc4+1] + T1[lc4+1][r];
            o2.z = T2[r][lc4+2] + T1[lc4+2][r];
            o2.w = T2[r][lc4+3] + T1[lc4+3][r];
            *(float4*)(Dm + (size_t)(bj*64 + r) * NN + bi*64 + lc4) = o2;
        }
    }
}

// ---------------------------------------------------------------------------
// Softmax row stats + sparse extraction. P[i][j] = ci + v_ij (v=0 off-support).
// Rows padded to a multiple of 8 with (col=0,val=0) so spmm can run fixed
// unroll-8 chunks. Entries beyond CAP spill to overflow list (exactness).
// ---------------------------------------------------------------------------
__global__ __launch_bounds__(256) void stats_extract_kernel(
    const float* __restrict__ A, float* __restrict__ cvec, int* __restrict__ nnz,
    int* __restrict__ cols, float* __restrict__ vals,
    int* __restrict__ ovf_cnt, int* __restrict__ ovf_row,
    int* __restrict__ ovf_col, float* __restrict__ ovf_val)
{
    __shared__ float srow[NN];
    __shared__ float red[8];
    __shared__ int cnt;
    const int row = blockIdx.x, t = threadIdx.x;
    const int lane = t & 63, wid = t >> 6;
    const float* src = A + (size_t)row * NN;

    float mx = -1e30f;
    #pragma unroll
    for (int c = 0; c < 4; ++c) {
        const int base = c*1024 + t*4;
        float4 v = *(const float4*)(src + base);
        *(float4*)&srow[base] = v;
        mx = fmaxf(mx, fmaxf(fmaxf(v.x, v.y), fmaxf(v.z, v.w)));
    }
    for (int off = 32; off; off >>= 1) mx = fmaxf(mx, __shfl_xor(mx, off));
    if (lane == 0) red[wid] = mx;
    __syncthreads();
    mx = fmaxf(fmaxf(red[0], red[1]), fmaxf(red[2], red[3]));

    float sum = 0.0f;
    #pragma unroll
    for (int c = 0; c < 4; ++c) {
        const int base = c*1024 + t*4;
        float4 v = *(float4*)&srow[base];
        sum += expf(v.x-mx) + expf(v.y-mx) + expf(v.z-mx) + expf(v.w-mx);
    }
    for (int off = 32; off; off >>= 1) sum += __shfl_xor(sum, off);
    if (lane == 0) red[4 + wid] = sum;
    if (t == 0) cnt = 0;
    __syncthreads();
    sum = red[4] + red[5] + red[6] + red[7];
    const float ci = expf(-mx) / sum;
    if (t == 0) cvec[row] = ci;

    for (int c = 0; c < 16; ++c) {
        const int j = c*256 + t;
        const float a = srow[j];
        if (a != 0.0f) {
            const float v = expf(a - mx)/sum - ci;
            int p = atomicAdd(&cnt, 1);
            if (p < CAP) {
                cols[(size_t)row*CAP + p] = j;
                vals[(size_t)row*CAP + p] = v;
            } else {
                int q = atomicAdd(ovf_cnt, 1);
                if (q < OVF_CAP) {
                    ovf_row[q] = row;
                    ovf_col[q] = j;
                    ovf_val[q] = v;
                }
            }
        }
    }
    __syncthreads();
    if (t == 0) {
        const int c2 = min(cnt, CAP);
        const int e2 = min((c2 + 7) & ~7, CAP);   // pad to multiple of 8
        for (int p = c2; p < e2; ++p) {
            cols[(size_t)row*CAP + p] = 0;
            vals[(size_t)row*CAP + p] = 0.0f;     // weight-0 gather of row 0: no-op
        }
        nnz[row] = e2 == c2 ? c2 : e2;            // padded count (multiple of 8)
    }
}

// ---------------------------------------------------------------------------
// Column sums of X [NN][DIN], two-stage deterministic (head-invariant; run
// once per kernel_launch). For the tpow chain, colsum is instead accumulated
// by spmm's epilogue into part[32][DIN] and drained below.
// ---------------------------------------------------------------------------
__global__ __launch_bounds__(256) void colsum_partial_kernel(
    const float* __restrict__ Y, float* __restrict__ part)
{
    const int cc = blockIdx.y * 256 + threadIdx.x;
    const int r0 = blockIdx.x * 128;
    float s = 0.0f;
    for (int r = 0; r < 128; ++r) s += Y[(size_t)(r0 + r) * DIN + cc];
    part[(size_t)blockIdx.x * DIN + cc] = s;
}

__global__ __launch_bounds__(256) void colsum_final_kernel(
    const float* __restrict__ part, float* __restrict__ colsum)
{
    const int cc = blockIdx.x * 256 + threadIdx.x;
    float s = 0.0f;
    #pragma unroll
    for (int r = 0; r < 32; ++r) s += part[(size_t)r * DIN + cc];
    colsum[cc] = s;
}

// ---------------------------------------------------------------------------
// Drain spmm-accumulated column sums: colsum[c] = sum_r part[r][c], and
// re-zero part so the next spmm can accumulate (invariant: part == 0 before
// every part-enabled spmm; established once by hipMemsetAsync).
// ---------------------------------------------------------------------------
__global__ __launch_bounds__(256) void colsum_drain_kernel(
    float* __restrict__ part, float* __restrict__ colsum)
{
    const int c = blockIdx.x * 256 + threadIdx.x;
    float s = 0.0f;
    #pragma unroll
    for (int r = 0; r < 32; ++r) {
        s += part[(size_t)r * DIN + c];
        part[(size_t)r * DIN + c] = 0.0f;
    }
    colsum[c] = s;
}

// ---------------------------------------------------------------------------
// Panel-blocked sparse+rank-1 application, XCD-pinned panels, float4 gathers
// (two sparse entries per VMEM instruction). Rounds 2/5/6/9 bracket this as
// the L2-line-service floor of the gather structure (~11.4 TB/s aggregate).
//
// Round 11 fusions (epilogue only; gather loop untouched):
//  - overflow fixup folded in: each block scans the (normally empty) ovf
//    list for its row, adding v*Y[j][panel] into the accumulator BEFORE mode
//    scaling (reproduces old fixup's scale semantics deterministically).
//    Removes 24 launches.
//  - column sums folded in: when do_part, each half0 lane atomically adds
//    its stored value into part[rowblk&31][col]; colsum_drain (1 tiny launch)
//    replaces the colsum_partial+final pair. Removes 20 launches + 640MB of
//    re-reads. Atomic order makes colsum ulp-nondeterministic (tolerated).
// mode 0: write; mode 1: write 0.25x; mode 2: += 0.25x
// ---------------------------------------------------------------------------
typedef float vf4 __attribute__((ext_vector_type(4)));

#define SPMM_LOAD(buf, b)                                               \
    _Pragma("unroll")                                                   \
    for (int u = 0; u < 4; ++u) {                                       \
        const int j = half ? rc[(b) + 2*u + 1] : rc[(b) + 2*u];         \
        buf[u] = *(const float4*)(Y + (size_t)j * DIN + cq);            \
    }

#define SPMM_FMA(buf, b)                                                \
    _Pragma("unroll")                                                   \
    for (int u = 0; u < 4; ++u) {                                       \
        const float v = half ? rv[(b) + 2*u + 1] : rv[(b) + 2*u];       \
        ax = fmaf(v, buf[u].x, ax);                                     \
        ay = fmaf(v, buf[u].y, ay);                                     \
        az = fmaf(v, buf[u].z, az);                                     \
        aw = fmaf(v, buf[u].w, aw);                                     \
    }

__global__ __launch_bounds__(256) void spmm_kernel(
    const float* __restrict__ Y, const float* __restrict__ colsum,
    const float* __restrict__ cvec, const int* __restrict__ nnz,
    const int* __restrict__ cols, const float* __restrict__ vals,
    float* __restrict__ Yout, int mode,
    const int* __restrict__ ovf_cnt, const int* __restrict__ ovf_row,
    const int* __restrict__ ovf_col, const float* __restrict__ ovf_val,
    float* __restrict__ part, int do_part)
{
    const int wave = threadIdx.x >> 6, lane = threadIdx.x & 63;
    const int half = lane >> 5;             // half-wave: even/odd entry stream
    const int qc   = (lane & 31) * 4;       // col-block within panel (float4)

    // XCD-affinity swizzle: same XCD -> same panel for a long stretch.
    const int id     = blockIdx.x;          // 0 .. 16383
    const int xcd    = id & 7;
    const int w      = id >> 3;             // 0 .. 2047 within this XCD
    const int panel  = xcd + ((w & 1024) ? 8 : 0);   // 16 panels of PW cols
    const int rowblk = w & 1023;            // 0 .. 1023 (4 rows each)

    const int row = __builtin_amdgcn_readfirstlane(rowblk * 4 + wave);
    const int cq  = panel * PW + qc;

    const int n = nnz[row];               // multiple of 8 (padded), scalar
    const float ci = cvec[row];
    const int*   rc = cols + (size_t)row * CAP;   // SGPR base -> s_load
    const float* rv = vals + (size_t)row * CAP;

    const float4 s = *(const float4*)(colsum + cq);
    // rank-1 term counted once (half 0 only); halves summed at the end.
    float ax = half ? 0.0f : ci * s.x;
    float ay = half ? 0.0f : ci * s.y;
    float az = half ? 0.0f : ci * s.z;
    float aw = half ? 0.0f : ci * s.w;

    float4 yA[4], yB[4];
    SPMM_LOAD(yA, 0);
    int base = 8;
    bool tailA = true;
    while (base < n) {
        SPMM_LOAD(yB, base);
        SPMM_FMA(yA, base - 8);
        base += 8;
        if (base < n) {
            SPMM_LOAD(yA, base);
            SPMM_FMA(yB, base - 8);
            base += 8;
        } else {
            SPMM_FMA(yB, base - 8);
            tailA = false;
            break;
        }
    }
    if (tailA) { SPMM_FMA(yA, base - 8); }

    // combine half-wave partials (lane l <-> l+32 hold the same col-block)
    ax += __shfl_xor(ax, 32);
    ay += __shfl_xor(ay, 32);
    az += __shfl_xor(az, 32);
    aw += __shfl_xor(aw, 32);

    // overflow entries (exactness for rows with nnz > CAP; cnt==0 in practice)
    const int ocnt = min(*ovf_cnt, OVF_CAP);
    for (int e = 0; e < ocnt; ++e) {
        if (ovf_row[e] == row) {                   // wave-uniform
            const int j = ovf_col[e];
            const float v = ovf_val[e];
            if (half == 0) {
                const float4 yv = *(const float4*)(Y + (size_t)j * DIN + cq);
                ax = fmaf(v, yv.x, ax);
                ay = fmaf(v, yv.y, ay);
                az = fmaf(v, yv.z, az);
                aw = fmaf(v, yv.w, aw);
            }
        }
    }

    if (half == 0) {
        float* dst = Yout + (size_t)row * DIN + cq;
        vf4 o;
        if (mode == 0)      { o[0] = ax;       o[1] = ay;       o[2] = az;       o[3] = aw; }
        else if (mode == 1) { o[0] = 0.25f*ax; o[1] = 0.25f*ay; o[2] = 0.25f*az; o[3] = 0.25f*aw; }
        else {
            const vf4 p = __builtin_nontemporal_load((const vf4*)dst);
            o[0] = p[0] + 0.25f*ax; o[1] = p[1] + 0.25f*ay;
            o[2] = p[2] + 0.25f*az; o[3] = p[3] + 0.25f*aw;
        }
        __builtin_nontemporal_store(o, (vf4*)dst);

        if (do_part) {
            float* pp = part + (size_t)(rowblk & 31) * DIN + cq;
            atomicAdd(pp + 0, o[0]);
            atomicAdd(pp + 1, o[1]);
            atomicAdd(pp + 2, o[2]);
            atomicAdd(pp + 3, o[3]);
        }
    }
}

// ---------------------------------------------------------------------------
extern "C" void kernel_launch(void* const* d_in, const int* in_sizes, int n_in,
                              void* d_out, int out_size, void* d_ws, size_t ws_size,
                              hipStream_t stream)
{
    const float* X  = (const float*)d_in[0];
    const float* Wq = (const float*)d_in[1];
    const float* bq = (const float*)d_in[2];
    const float* Wk = (const float*)d_in[3];
    const float* bk = (const float*)d_in[4];
    float* out = (float*)d_out;

    // Batched layout needs 4-head q/k buffers (+24MB vs fallback). Guarded by
    // ws_size; fallback is the proven per-head path.
    const size_t nf_batched = 8ull*NN*HID + (size_t)NN*NN + 2ull*(size_t)NN*CAP
                            + 32ull*DIN + 2ull*DIN + 8ull*NN /*sqq,sqk*/
                            + 3ull*NN /*mdp,kth,cvec*/ + (size_t)NN /*nnz*/
                            + 16 + 3ull*OVF_CAP;
    const bool batched = ws_size >= nf_batched * sizeof(float);
    const int nhq = batched ? NHEADS : 1;   // heads resident in q/k buffers

    float* ws    = (float*)d_ws;
    float* qbufs = ws;                                      // nhq*NN*HID
    float* kbufs = qbufs + (size_t)nhq*NN*HID;              // nhq*NN*HID
    float* A     = kbufs + (size_t)nhq*NN*HID;              // NN*NN (64MB)
    float* Y1    = A;                                       // overlays A
    float* Y2    = A + (size_t)NN*DIN;                      // overlays A upper half
    float* valsA = A + (size_t)NN*NN;                       // NN*CAP
    int*   colsA = (int*)(valsA + (size_t)NN*CAP);          // NN*CAP
    float* part  = (float*)(colsA + (size_t)NN*CAP);        // 32*DIN
    float* colsumX = part + 32*DIN;                         // DIN (colsum of X, head-invariant)
    float* colsumB = colsumX + DIN;                         // DIN (per-iteration colsum)
    float* sqq  = colsumB + DIN;                            // nhq*NN
    float* sqk  = sqq + (size_t)nhq*NN;                     // nhq*NN
    float* mdp  = sqk + (size_t)nhq*NN;
    float* kth  = mdp + NN;
    float* cvec = kth + NN;
    int*   nnz  = (int*)(cvec + NN);
    int*   ovf_cnt = nnz + NN;
    int*   ovf_row = ovf_cnt + 16;
    int*   ovf_col = ovf_row + OVF_CAP;
    float* ovf_val = (float*)(ovf_col + OVF_CAP);

    if (batched) {
        // All 4 heads x {q,k} in one launch: 2048 blocks (8/CU) vs 4x512.
        proj_kernel<<<dim3(NN/64, HID/64, 2*NHEADS), 256, 0, stream>>>(
            X, Wq, bq, Wk, bk, qbufs, kbufs, 0);
        rownorm_kernel<<<dim3(NN, 2, NHEADS), 64, 0, stream>>>(qbufs, kbufs, sqq, sqk);
    }
    // colsum(X) is head-invariant (tpow=1 src is always X): compute once.
    colsum_partial_kernel<<<dim3(32, DIN/256), 256, 0, stream>>>(X, part);
    colsum_final_kernel<<<dim3(DIN/256), 256, 0, stream>>>(part, colsumX);
    // Establish the part==0 invariant for spmm's fused colsum accumulation.
    hipMemsetAsync(part, 0, 32ull * DIN * sizeof(float), stream);

    for (int h = 0; h < NHEADS; ++h) {
        if (!batched) {
            proj_kernel<<<dim3(NN/64, HID/64, 2), 256, 0, stream>>>(
                X, Wq, bq, Wk, bk, qbufs, kbufs, h);
            rownorm_kernel<<<dim3(NN, 2, 1), 64, 0, stream>>>(qbufs, kbufs, sqq, sqk);
        }
        const size_t ho = batched ? (size_t)h : 0;
        const float* qh   = qbufs + ho * NN * HID;
        const float* kh   = kbufs + ho * NN * HID;
        const float* sqqh = sqq + ho * NN;
        const float* sqkh = sqk + ho * NN;

        dist_kernel<<<dim3(NN/64, NN/64), 256, 0, stream>>>(qh, kh, sqqh, sqkh, A);
        select_kernel<<<dim3(NN), 64, 0, stream>>>(A, mdp, kth);
        affsym_kernel<<<dim3(2080), 256, 0, stream>>>(A, mdp, kth, ovf_cnt);
        stats_extract_kernel<<<dim3(NN), 256, 0, stream>>>(A, cvec, nnz, colsA, valsA,
                                                           ovf_cnt, ovf_row, ovf_col, ovf_val);

        const float* src = X;
        for (int tpow = 1; tpow <= 6; ++tpow) {
            const float* cs;
            if (tpow == 1) {
                cs = colsumX;   // precomputed, head-invariant
            } else {
                // drain the previous spmm's fused colsum accumulation
                colsum_drain_kernel<<<dim3(DIN/256), 256, 0, stream>>>(part, colsumB);
                cs = colsumB;
            }
            float* dst;
            int mode;
            if (tpow == 6)      { dst = out; mode = (h == 0) ? 1 : 2; }
            else if (tpow & 1)  { dst = Y1;  mode = 0; }
            else                { dst = Y2;  mode = 0; }
            const int do_part = (tpow < 6) ? 1 : 0;   // t=6 output needs no colsum
            spmm_kernel<<<dim3((NN/4) * (DIN/PW)), 256, 0, stream>>>(
                src, cs, cvec, nnz, colsA, valsA, dst, mode,
                ovf_cnt, ovf_row, ovf_col, ovf_val, part, do_part);
            src = dst;
        }
    }
}

// Round 12
// 15573.535 us; speedup vs baseline: 1.0505x; 1.0505x over previous
//
#include <hip/hip_runtime.h>
#include <hip/hip_bf16.h>
#include <math.h>

#define NN 4096
#define DIN 2048
#define HID 256
#define NHEADS 4
#define CAP 1024       // fast-path nnz per row; multiple of 8 (padding invariant)
#define OVF_CAP 131072 // spill capacity for rows exceeding CAP (exactness guarantee)
#define PW 128         // spmm panel width (floats): 4096*PW*4B = 2MB panel -> fits one XCD L2

// ---------------------------------------------------------------------------
// Projection GEMM (NT): out[n][c] = sum_d X[n][d]*W[c][d] + b[c]
// 64x64 tile, 4x4 per thread. Head-batched: blockIdx.z = head*2 + isK
// (grid z=8, 2048 blocks = 8/CU; round-8 counters: occupancy 5.7->62%).
// ---------------------------------------------------------------------------
__global__ __launch_bounds__(256) void proj_kernel(
    const float* __restrict__ X, const float* __restrict__ Wq, const float* __restrict__ bq,
    const float* __restrict__ Wk, const float* __restrict__ bk,
    float* __restrict__ qb, float* __restrict__ kb, int h0)
{
    const int isK  = blockIdx.z & 1;
    const int hidx = blockIdx.z >> 1;        // head index within this launch
    const int hh   = h0 + hidx;              // weight head
    const float* W    = (isK ? Wk : Wq) + (size_t)hh * HID * DIN;
    const float* bias = (isK ? bk : bq) + hh * HID;
    float* out = (isK ? kb : qb) + (size_t)hidx * NN * HID;

    const int bm = blockIdx.x * 64;
    const int bn = blockIdx.y * 64;
    const int t  = threadIdx.x;
    const int tx = t & 15, ty = t >> 4;
    const int lr = t >> 2, lk = (t & 3) * 4;

    __shared__ float As[16][68];
    __shared__ float Bs[16][68];
    float acc[4][4] = {};

    for (int k0 = 0; k0 < DIN; k0 += 16) {
        float4 av = *(const float4*)(X + (size_t)(bm + lr) * DIN + k0 + lk);
        float4 bv = *(const float4*)(W + (size_t)(bn + lr) * DIN + k0 + lk);
        As[lk+0][lr]=av.x; As[lk+1][lr]=av.y; As[lk+2][lr]=av.z; As[lk+3][lr]=av.w;
        Bs[lk+0][lr]=bv.x; Bs[lk+1][lr]=bv.y; Bs[lk+2][lr]=bv.z; Bs[lk+3][lr]=bv.w;
        __syncthreads();
        #pragma unroll
        for (int kk = 0; kk < 16; ++kk) {
            const float4 a4 = *(const float4*)&As[kk][ty*4];
            const float4 b4 = *(const float4*)&Bs[kk][tx*4];
            const float a[4] = {a4.x,a4.y,a4.z,a4.w};
            const float b[4] = {b4.x,b4.y,b4.z,b4.w};
            #pragma unroll
            for (int i = 0; i < 4; ++i)
                #pragma unroll
                for (int j = 0; j < 4; ++j)
                    acc[i][j] = fmaf(a[i], b[j], acc[i][j]);
        }
        __syncthreads();
    }
    #pragma unroll
    for (int i = 0; i < 4; ++i) {
        const int m = bm + ty*4 + i;
        float4 o;
        o.x = acc[i][0] + bias[bn+tx*4+0];
        o.y = acc[i][1] + bias[bn+tx*4+1];
        o.z = acc[i][2] + bias[bn+tx*4+2];
        o.w = acc[i][3] + bias[bn+tx*4+3];
        *(float4*)(out + (size_t)m * HID + bn + tx*4) = o;
    }
}

// ---------------------------------------------------------------------------
// Row sum-of-squares; head-batched via blockIdx.z (0 in fallback mode).
// ---------------------------------------------------------------------------
__global__ __launch_bounds__(64) void rownorm_kernel(
    const float* __restrict__ q, const float* __restrict__ k,
    float* __restrict__ sqq, float* __restrict__ sqk)
{
    const int row = blockIdx.x;
    const int hz  = blockIdx.z;
    const int lane = threadIdx.x;
    const float* src = (blockIdx.y ? k : q) + ((size_t)hz * NN + row) * HID;
    float4 v = *(const float4*)(src + lane * 4);
    float s = v.x*v.x + v.y*v.y + v.z*v.z + v.w*v.w;
    for (int off = 32; off; off >>= 1) s += __shfl_down(s, off);
    if (lane == 0) (blockIdx.y ? sqk : sqq)[(size_t)hz * NN + row] = s;
}

// ---------------------------------------------------------------------------
// Gram GEMM (NT, K=HID) + distance epilogue. 64x64 proven config.
// ---------------------------------------------------------------------------
__global__ __launch_bounds__(256) void dist_kernel(
    const float* __restrict__ q, const float* __restrict__ k,
    const float* __restrict__ sqq, const float* __restrict__ sqk,
    float* __restrict__ Dm)
{
    const int bm = blockIdx.x * 64;
    const int bn = blockIdx.y * 64;
    const int t  = threadIdx.x;
    const int tx = t & 15, ty = t >> 4;
    const int lr = t >> 2, lk = (t & 3) * 4;

    __shared__ float As[16][68];
    __shared__ float Bs[16][68];
    float acc[4][4] = {};

    for (int k0 = 0; k0 < HID; k0 += 16) {
        float4 av = *(const float4*)(q + (size_t)(bm + lr) * HID + k0 + lk);
        float4 bv = *(const float4*)(k + (size_t)(bn + lr) * HID + k0 + lk);
        As[lk+0][lr]=av.x; As[lk+1][lr]=av.y; As[lk+2][lr]=av.z; As[lk+3][lr]=av.w;
        Bs[lk+0][lr]=bv.x; Bs[lk+1][lr]=bv.y; Bs[lk+2][lr]=bv.z; Bs[lk+3][lr]=bv.w;
        __syncthreads();
        #pragma unroll
        for (int kk = 0; kk < 16; ++kk) {
            const float4 a4 = *(const float4*)&As[kk][ty*4];
            const float4 b4 = *(const float4*)&Bs[kk][tx*4];
            const float a[4] = {a4.x,a4.y,a4.z,a4.w};
            const float b[4] = {b4.x,b4.y,b4.z,b4.w};
            #pragma unroll
            for (int i = 0; i < 4; ++i)
                #pragma unroll
                for (int j = 0; j < 4; ++j)
                    acc[i][j] = fmaf(a[i], b[j], acc[i][j]);
        }
        __syncthreads();
    }
    #pragma unroll
    for (int i = 0; i < 4; ++i) {
        const int m = bm + ty*4 + i;
        const float sm = sqq[m];
        float4 o;
        float v0 = sm + sqk[bn+tx*4+0] - 2.0f*acc[i][0];
        float v1 = sm + sqk[bn+tx*4+1] - 2.0f*acc[i][1];
        float v2 = sm + sqk[bn+tx*4+2] - 2.0f*acc[i][2];
        float v3 = sm + sqk[bn+tx*4+3] - 2.0f*acc[i][3];
        o.x = sqrtf(fmaxf(v0, 0.0f) + 1e-10f);
        o.y = sqrtf(fmaxf(v1, 0.0f) + 1e-10f);
        o.z = sqrtf(fmaxf(v2, 0.0f) + 1e-10f);
        o.w = sqrtf(fmaxf(v3, 0.0f) + 1e-10f);
        *(float4*)(Dm + (size_t)m * NN + bn + tx*4) = o;
    }
}

// ---------------------------------------------------------------------------
// Per-row order stats: 11th and 30th smallest via register-resident radix
// bisection + ballot counting (no LDS; bit-identical ranks).
// ---------------------------------------------------------------------------
__device__ __forceinline__ unsigned kth_reg(const unsigned (&r)[64], int K)
{
    unsigned lo = 0u, hi = 0xFFFFFFFFu;
    while (lo < hi) {
        unsigned mid = lo + ((hi - lo) >> 1);
        int c = 0;
        #pragma unroll
        for (int i = 0; i < 64; ++i)
            c += (int)__popcll(__ballot(r[i] <= mid));
        if (c >= K) hi = mid; else lo = mid + 1;
    }
    return lo;
}

__global__ __launch_bounds__(64) void select_kernel(
    const float* __restrict__ Dm, float* __restrict__ mdp, float* __restrict__ kth)
{
    const int row = blockIdx.x;
    const int lane = threadIdx.x;
    const float* src = Dm + (size_t)row * NN + lane * 64;  // per-lane contiguous 256B
    unsigned r[64];
    #pragma unroll
    for (int c = 0; c < 16; ++c) {
        float4 v = *(const float4*)(src + c * 4);
        r[c*4+0] = __float_as_uint(v.x);
        r[c*4+1] = __float_as_uint(v.y);
        r[c*4+2] = __float_as_uint(v.z);
        r[c*4+3] = __float_as_uint(v.w);
    }
    unsigned v11 = kth_reg(r, 11);   // sort(d)[10]
    unsigned v30 = kth_reg(r, 30);   // sort(d)[29]
    if (lane == 0) {
        float md = __uint_as_float(v11) + 1e-10f;
        float t  = __uint_as_float(v30) / md;
        mdp[row] = md;
        kth[row] = expf(-(t*t));   // same expr as affsym -> identical rounding
    }
}

// ---------------------------------------------------------------------------
// FUSED affinity + symmetrize: A := aff(D) + aff(D)^T in one pass (round 10:
// one 128MB pass and 8 launches eliminated; bit-identical A). Block 0 also
// zeroes ovf_cnt (stream order: affsym completes before stats_extract).
// ---------------------------------------------------------------------------
__device__ __forceinline__ void aff4(float4& v, float m, float kt, bool diagtile,
                                     int r, int lc4)
{
    float t0 = v.x / m, t1 = v.y / m, t2 = v.z / m, t3 = v.w / m;
    float a0 = expf(-(t0*t0)), a1 = expf(-(t1*t1)), a2 = expf(-(t2*t2)), a3 = expf(-(t3*t3));
    a0 = (a0 >= kt) ? a0 : 0.0f;
    a1 = (a1 >= kt) ? a1 : 0.0f;
    a2 = (a2 >= kt) ? a2 : 0.0f;
    a3 = (a3 >= kt) ? a3 : 0.0f;
    if (diagtile) {
        if (lc4+0 == r) a0 = 1.0f;
        if (lc4+1 == r) a1 = 1.0f;
        if (lc4+2 == r) a2 = 1.0f;
        if (lc4+3 == r) a3 = 1.0f;
    }
    v.x = a0; v.y = a1; v.z = a2; v.w = a3;
}

__global__ __launch_bounds__(256) void affsym_kernel(
    float* __restrict__ Dm, const float* __restrict__ mdp, const float* __restrict__ kthv,
    int* __restrict__ ovf_cnt)
{
    if (blockIdx.x == 0 && threadIdx.x == 0) *ovf_cnt = 0;

    int rem = blockIdx.x;
    int bi = 0;
    while (rem >= 64 - bi) { rem -= 64 - bi; ++bi; }
    const int bj = bi + rem;
    const bool diagtile = (bi == bj);

    __shared__ float T1[64][65];
    __shared__ float T2[64][65];
    const int t = threadIdx.x;
    const int lr = t >> 4;
    const int lc4 = (t & 15) * 4;

    #pragma unroll
    for (int rr = 0; rr < 4; ++rr) {
        const int r = rr*16 + lr;
        {
            const int grow = bi*64 + r;
            const float m  = mdp[grow];
            const float kt = kthv[grow];
            float4 v1 = *(const float4*)(Dm + (size_t)grow * NN + bj*64 + lc4);
            aff4(v1, m, kt, diagtile, r, lc4);
            T1[r][lc4+0]=v1.x; T1[r][lc4+1]=v1.y; T1[r][lc4+2]=v1.z; T1[r][lc4+3]=v1.w;
        }
        {
            const int grow = bj*64 + r;
            const float m  = mdp[grow];
            const float kt = kthv[grow];
            float4 v2 = *(const float4*)(Dm + (size_t)grow * NN + bi*64 + lc4);
            aff4(v2, m, kt, diagtile, r, lc4);
            T2[r][lc4+0]=v2.x; T2[r][lc4+1]=v2.y; T2[r][lc4+2]=v2.z; T2[r][lc4+3]=v2.w;
        }
    }
    __syncthreads();
    #pragma unroll
    for (int rr = 0; rr < 4; ++rr) {
        const int r = rr*16 + lr;
        float4 o1;
        o1.x = T1[r][lc4+0] + T2[lc4+0][r];
        o1.y = T1[r][lc4+1] + T2[lc4+1][r];
        o1.z = T1[r][lc4+2] + T2[lc4+2][r];
        o1.w = T1[r][lc4+3] + T2[lc4+3][r];
        *(float4*)(Dm + (size_t)(bi*64 + r) * NN + bj*64 + lc4) = o1;
        if (!diagtile) {
            float4 o2;
            o2.x = T2[r][lc4+0] + T1[lc4+0][r];
            o2.y = T2[r][lc4+1] + T1[lc4+1][r];
            o2.z = T2[r][lc4+2] + T1[lc4+2][r];
            o2.w = T2[r][lc4+3] + T1[lc4+3][r];
            *(float4*)(Dm + (size_t)(bj*64 + r) * NN + bi*64 + lc4) = o2;
        }
    }
}

// ---------------------------------------------------------------------------
// Softmax row stats + sparse extraction. P[i][j] = ci + v_ij (v=0 off-support).
// Rows padded to a multiple of 8 with (col=0,val=0) so spmm can run fixed
// unroll-8 chunks. Entries beyond CAP spill to overflow list (exactness).
// ---------------------------------------------------------------------------
__global__ __launch_bounds__(256) void stats_extract_kernel(
    const float* __restrict__ A, float* __restrict__ cvec, int* __restrict__ nnz,
    int* __restrict__ cols, float* __restrict__ vals,
    int* __restrict__ ovf_cnt, int* __restrict__ ovf_row,
    int* __restrict__ ovf_col, float* __restrict__ ovf_val)
{
    __shared__ float srow[NN];
    __shared__ float red[8];
    __shared__ int cnt;
    const int row = blockIdx.x, t = threadIdx.x;
    const int lane = t & 63, wid = t >> 6;
    const float* src = A + (size_t)row * NN;

    float mx = -1e30f;
    #pragma unroll
    for (int c = 0; c < 4; ++c) {
        const int base = c*1024 + t*4;
        float4 v = *(const float4*)(src + base);
        *(float4*)&srow[base] = v;
        mx = fmaxf(mx, fmaxf(fmaxf(v.x, v.y), fmaxf(v.z, v.w)));
    }
    for (int off = 32; off; off >>= 1) mx = fmaxf(mx, __shfl_xor(mx, off));
    if (lane == 0) red[wid] = mx;
    __syncthreads();
    mx = fmaxf(fmaxf(red[0], red[1]), fmaxf(red[2], red[3]));

    float sum = 0.0f;
    #pragma unroll
    for (int c = 0; c < 4; ++c) {
        const int base = c*1024 + t*4;
        float4 v = *(float4*)&srow[base];
        sum += expf(v.x-mx) + expf(v.y-mx) + expf(v.z-mx) + expf(v.w-mx);
    }
    for (int off = 32; off; off >>= 1) sum += __shfl_xor(sum, off);
    if (lane == 0) red[4 + wid] = sum;
    if (t == 0) cnt = 0;
    __syncthreads();
    sum = red[4] + red[5] + red[6] + red[7];
    const float ci = expf(-mx) / sum;
    if (t == 0) cvec[row] = ci;

    for (int c = 0; c < 16; ++c) {
        const int j = c*256 + t;
        const float a = srow[j];
        if (a != 0.0f) {
            const float v = expf(a - mx)/sum - ci;
            int p = atomicAdd(&cnt, 1);
            if (p < CAP) {
                cols[(size_t)row*CAP + p] = j;
                vals[(size_t)row*CAP + p] = v;
            } else {
                int q = atomicAdd(ovf_cnt, 1);
                if (q < OVF_CAP) {
                    ovf_row[q] = row;
                    ovf_col[q] = j;
                    ovf_val[q] = v;
                }
            }
        }
    }
    __syncthreads();
    if (t == 0) {
        const int c2 = min(cnt, CAP);
        const int e2 = min((c2 + 7) & ~7, CAP);   // pad to multiple of 8
        for (int p = c2; p < e2; ++p) {
            cols[(size_t)row*CAP + p] = 0;
            vals[(size_t)row*CAP + p] = 0.0f;     // weight-0 gather of row 0: no-op
        }
        nnz[row] = e2 == c2 ? c2 : e2;            // padded count (multiple of 8)
    }
}

// ---------------------------------------------------------------------------
// Column sums of Y [NN][DIN], two-stage deterministic. (Round 11's fused
// atomic colsum regressed 2.7x -- 16384 blocks x 128 atomicAdds onto a 256KB
// surface serialize at the coherence point. Streaming re-read is cheaper.)
// ---------------------------------------------------------------------------
__global__ __launch_bounds__(256) void colsum_partial_kernel(
    const float* __restrict__ Y, float* __restrict__ part)
{
    const int cc = blockIdx.y * 256 + threadIdx.x;
    const int r0 = blockIdx.x * 128;
    float s = 0.0f;
    for (int r = 0; r < 128; ++r) s += Y[(size_t)(r0 + r) * DIN + cc];
    part[(size_t)blockIdx.x * DIN + cc] = s;
}

__global__ __launch_bounds__(256) void colsum_final_kernel(
    const float* __restrict__ part, float* __restrict__ colsum)
{
    const int cc = blockIdx.x * 256 + threadIdx.x;
    float s = 0.0f;
    #pragma unroll
    for (int r = 0; r < 32; ++r) s += part[(size_t)r * DIN + cc];
    colsum[cc] = s;
}

// ---------------------------------------------------------------------------
// Panel-blocked sparse+rank-1 application, XCD-pinned panels, float4 gathers
// (two sparse entries per VMEM instruction). Rounds 2/5/6/9 bracket this as
// the L2-line-service floor of the gather structure (~11.4 TB/s aggregate).
//
// Round 12: overflow fixup folded into the epilogue (kept from round 11 --
// the safe half). *ovf_cnt == 0 in practice so the scan never executes
// (one wave-uniform scalar load); removes 24 empty fixup launches. The
// atomic colsum fusion (round 11's regression) is reverted.
// mode 0: write; mode 1: write 0.25x; mode 2: += 0.25x
// ---------------------------------------------------------------------------
typedef float vf4 __attribute__((ext_vector_type(4)));

#define SPMM_LOAD(buf, b)                                               \
    _Pragma("unroll")                                                   \
    for (int u = 0; u < 4; ++u) {                                       \
        const int j = half ? rc[(b) + 2*u + 1] : rc[(b) + 2*u];         \
        buf[u] = *(const float4*)(Y + (size_t)j * DIN + cq);            \
    }

#define SPMM_FMA(buf, b)                                                \
    _Pragma("unroll")                                                   \
    for (int u = 0; u < 4; ++u) {                                       \
        const float v = half ? rv[(b) + 2*u + 1] : rv[(b) + 2*u];       \
        ax = fmaf(v, buf[u].x, ax);                                     \
        ay = fmaf(v, buf[u].y, ay);                                     \
        az = fmaf(v, buf[u].z, az);                                     \
        aw = fmaf(v, buf[u].w, aw);                                     \
    }

__global__ __launch_bounds__(256) void spmm_kernel(
    const float* __restrict__ Y, const float* __restrict__ colsum,
    const float* __restrict__ cvec, const int* __restrict__ nnz,
    const int* __restrict__ cols, const float* __restrict__ vals,
    float* __restrict__ Yout, int mode,
    const int* __restrict__ ovf_cnt, const int* __restrict__ ovf_row,
    const int* __restrict__ ovf_col, const float* __restrict__ ovf_val)
{
    const int wave = threadIdx.x >> 6, lane = threadIdx.x & 63;
    const int half = lane >> 5;             // half-wave: even/odd entry stream
    const int qc   = (lane & 31) * 4;       // col-block within panel (float4)

    // XCD-affinity swizzle: same XCD -> same panel for a long stretch.
    const int id     = blockIdx.x;          // 0 .. 16383
    const int xcd    = id & 7;
    const int w      = id >> 3;             // 0 .. 2047 within this XCD
    const int panel  = xcd + ((w & 1024) ? 8 : 0);   // 16 panels of PW cols
    const int rowblk = w & 1023;            // 0 .. 1023 (4 rows each)

    const int row = __builtin_amdgcn_readfirstlane(rowblk * 4 + wave);
    const int cq  = panel * PW + qc;

    const int n = nnz[row];               // multiple of 8 (padded), scalar
    const float ci = cvec[row];
    const int*   rc = cols + (size_t)row * CAP;   // SGPR base -> s_load
    const float* rv = vals + (size_t)row * CAP;

    const float4 s = *(const float4*)(colsum + cq);
    // rank-1 term counted once (half 0 only); halves summed at the end.
    float ax = half ? 0.0f : ci * s.x;
    float ay = half ? 0.0f : ci * s.y;
    float az = half ? 0.0f : ci * s.z;
    float aw = half ? 0.0f : ci * s.w;

    float4 yA[4], yB[4];
    SPMM_LOAD(yA, 0);
    int base = 8;
    bool tailA = true;
    while (base < n) {
        SPMM_LOAD(yB, base);
        SPMM_FMA(yA, base - 8);
        base += 8;
        if (base < n) {
            SPMM_LOAD(yA, base);
            SPMM_FMA(yB, base - 8);
            base += 8;
        } else {
            SPMM_FMA(yB, base - 8);
            tailA = false;
            break;
        }
    }
    if (tailA) { SPMM_FMA(yA, base - 8); }

    // combine half-wave partials (lane l <-> l+32 hold the same col-block)
    ax += __shfl_xor(ax, 32);
    ay += __shfl_xor(ay, 32);
    az += __shfl_xor(az, 32);
    aw += __shfl_xor(aw, 32);

    // overflow entries (exactness for rows with nnz > CAP; cnt==0 in practice
    // so this loop never executes -- one wave-uniform scalar load)
    const int ocnt = min(*ovf_cnt, OVF_CAP);
    for (int e = 0; e < ocnt; ++e) {
        if (ovf_row[e] == row && half == 0) {      // wave-uniform predicate
            const int j = ovf_col[e];
            const float v = ovf_val[e];
            const float4 yv = *(const float4*)(Y + (size_t)j * DIN + cq);
            ax = fmaf(v, yv.x, ax);
            ay = fmaf(v, yv.y, ay);
            az = fmaf(v, yv.z, az);
            aw = fmaf(v, yv.w, aw);
        }
    }

    if (half == 0) {
        float* dst = Yout + (size_t)row * DIN + cq;
        vf4 o;
        if (mode == 0)      { o[0] = ax;       o[1] = ay;       o[2] = az;       o[3] = aw; }
        else if (mode == 1) { o[0] = 0.25f*ax; o[1] = 0.25f*ay; o[2] = 0.25f*az; o[3] = 0.25f*aw; }
        else {
            const vf4 p = __builtin_nontemporal_load((const vf4*)dst);
            o[0] = p[0] + 0.25f*ax; o[1] = p[1] + 0.25f*ay;
            o[2] = p[2] + 0.25f*az; o[3] = p[3] + 0.25f*aw;
        }
        __builtin_nontemporal_store(o, (vf4*)dst);
    }
}

// ---------------------------------------------------------------------------
extern "C" void kernel_launch(void* const* d_in, const int* in_sizes, int n_in,
                              void* d_out, int out_size, void* d_ws, size_t ws_size,
                              hipStream_t stream)
{
    const float* X  = (const float*)d_in[0];
    const float* Wq = (const float*)d_in[1];
    const float* bq = (const float*)d_in[2];
    const float* Wk = (const float*)d_in[3];
    const float* bk = (const float*)d_in[4];
    float* out = (float*)d_out;

    // Batched layout needs 4-head q/k buffers (+24MB vs fallback). Guarded by
    // ws_size; fallback is the proven per-head path.
    const size_t nf_batched = 8ull*NN*HID + (size_t)NN*NN + 2ull*(size_t)NN*CAP
                            + 32ull*DIN + 2ull*DIN + 8ull*NN /*sqq,sqk*/
                            + 3ull*NN /*mdp,kth,cvec*/ + (size_t)NN /*nnz*/
                            + 16 + 3ull*OVF_CAP;
    const bool batched = ws_size >= nf_batched * sizeof(float);
    const int nhq = batched ? NHEADS : 1;   // heads resident in q/k buffers

    float* ws    = (float*)d_ws;
    float* qbufs = ws;                                      // nhq*NN*HID
    float* kbufs = qbufs + (size_t)nhq*NN*HID;              // nhq*NN*HID
    float* A     = kbufs + (size_t)nhq*NN*HID;              // NN*NN (64MB)
    float* Y1    = A;                                       // overlays A
    float* Y2    = A + (size_t)NN*DIN;                      // overlays A upper half
    float* valsA = A + (size_t)NN*NN;                       // NN*CAP
    int*   colsA = (int*)(valsA + (size_t)NN*CAP);          // NN*CAP
    float* part  = (float*)(colsA + (size_t)NN*CAP);        // 32*DIN
    float* colsumX = part + 32*DIN;                         // DIN (colsum of X, head-invariant)
    float* colsumB = colsumX + DIN;                         // DIN (per-iteration colsum)
    float* sqq  = colsumB + DIN;                            // nhq*NN
    float* sqk  = sqq + (size_t)nhq*NN;                     // nhq*NN
    float* mdp  = sqk + (size_t)nhq*NN;
    float* kth  = mdp + NN;
    float* cvec = kth + NN;
    int*   nnz  = (int*)(cvec + NN);
    int*   ovf_cnt = nnz + NN;
    int*   ovf_row = ovf_cnt + 16;
    int*   ovf_col = ovf_row + OVF_CAP;
    float* ovf_val = (float*)(ovf_col + OVF_CAP);

    if (batched) {
        // All 4 heads x {q,k} in one launch: 2048 blocks (8/CU) vs 4x512.
        proj_kernel<<<dim3(NN/64, HID/64, 2*NHEADS), 256, 0, stream>>>(
            X, Wq, bq, Wk, bk, qbufs, kbufs, 0);
        rownorm_kernel<<<dim3(NN, 2, NHEADS), 64, 0, stream>>>(qbufs, kbufs, sqq, sqk);
    }
    // colsum(X) is head-invariant (tpow=1 src is always X): compute once.
    colsum_partial_kernel<<<dim3(32, DIN/256), 256, 0, stream>>>(X, part);
    colsum_final_kernel<<<dim3(DIN/256), 256, 0, stream>>>(part, colsumX);

    for (int h = 0; h < NHEADS; ++h) {
        if (!batched) {
            proj_kernel<<<dim3(NN/64, HID/64, 2), 256, 0, stream>>>(
                X, Wq, bq, Wk, bk, qbufs, kbufs, h);
            rownorm_kernel<<<dim3(NN, 2, 1), 64, 0, stream>>>(qbufs, kbufs, sqq, sqk);
        }
        const size_t ho = batched ? (size_t)h : 0;
        const float* qh   = qbufs + ho * NN * HID;
        const float* kh   = kbufs + ho * NN * HID;
        const float* sqqh = sqq + ho * NN;
        const float* sqkh = sqk + ho * NN;

        dist_kernel<<<dim3(NN/64, NN/64), 256, 0, stream>>>(qh, kh, sqqh, sqkh, A);
        select_kernel<<<dim3(NN), 64, 0, stream>>>(A, mdp, kth);
        affsym_kernel<<<dim3(2080), 256, 0, stream>>>(A, mdp, kth, ovf_cnt);
        stats_extract_kernel<<<dim3(NN), 256, 0, stream>>>(A, cvec, nnz, colsA, valsA,
                                                           ovf_cnt, ovf_row, ovf_col, ovf_val);

        const float* src = X;
        for (int tpow = 1; tpow <= 6; ++tpow) {
            const float* cs;
            if (tpow == 1) {
                cs = colsumX;   // precomputed, head-invariant
            } else {
                colsum_partial_kernel<<<dim3(32, DIN/256), 256, 0, stream>>>(src, part);
                colsum_final_kernel<<<dim3(DIN/256), 256, 0, stream>>>(part, colsumB);
                cs = colsumB;
            }
            float* dst;
            int mode;
            if (tpow == 6)      { dst = out; mode = (h == 0) ? 1 : 2; }
            else if (tpow & 1)  { dst = Y1;  mode = 0; }
            else                { dst = Y2;  mode = 0; }
            spmm_kernel<<<dim3((NN/4) * (DIN/PW)), 256, 0, stream>>>(
                src, cs, cvec, nnz, colsA, valsA, dst, mode,
                ovf_cnt, ovf_row, ovf_col, ovf_val);
            src = dst;
        }
    }
}

// Round 13
// 6151.854 us; speedup vs baseline: 2.6595x; 2.5315x over previous
//
#include <hip/hip_runtime.h>
#include <hip/hip_bf16.h>
#include <math.h>

#define NN 4096
#define DIN 2048
#define HID 256
#define NHEADS 4
#define CAP 1024       // fast-path nnz per row; multiple of 8 (padding invariant)
#define OVF_CAP 131072 // spill capacity for rows exceeding CAP (exactness guarantee)
#define PW 128         // spmm panel width (floats): 4096*PW*4B = 2MB panel -> fits one XCD L2

// ---------------------------------------------------------------------------
// Projection GEMM (NT): out[n][c] = sum_d X[n][d]*W[c][d] + b[c]
// 64x64 tile, 4x4 per thread. Head-batched: blockIdx.z = head*2 + isK
// (grid z=8, 2048 blocks = 8/CU; round-8 counters: occupancy 5.7->62%).
// ---------------------------------------------------------------------------
__global__ __launch_bounds__(256) void proj_kernel(
    const float* __restrict__ X, const float* __restrict__ Wq, const float* __restrict__ bq,
    const float* __restrict__ Wk, const float* __restrict__ bk,
    float* __restrict__ qb, float* __restrict__ kb, int h0)
{
    const int isK  = blockIdx.z & 1;
    const int hidx = blockIdx.z >> 1;        // head index within this launch
    const int hh   = h0 + hidx;              // weight head
    const float* W    = (isK ? Wk : Wq) + (size_t)hh * HID * DIN;
    const float* bias = (isK ? bk : bq) + hh * HID;
    float* out = (isK ? kb : qb) + (size_t)hidx * NN * HID;

    const int bm = blockIdx.x * 64;
    const int bn = blockIdx.y * 64;
    const int t  = threadIdx.x;
    const int tx = t & 15, ty = t >> 4;
    const int lr = t >> 2, lk = (t & 3) * 4;

    __shared__ float As[16][68];
    __shared__ float Bs[16][68];
    float acc[4][4] = {};

    for (int k0 = 0; k0 < DIN; k0 += 16) {
        float4 av = *(const float4*)(X + (size_t)(bm + lr) * DIN + k0 + lk);
        float4 bv = *(const float4*)(W + (size_t)(bn + lr) * DIN + k0 + lk);
        As[lk+0][lr]=av.x; As[lk+1][lr]=av.y; As[lk+2][lr]=av.z; As[lk+3][lr]=av.w;
        Bs[lk+0][lr]=bv.x; Bs[lk+1][lr]=bv.y; Bs[lk+2][lr]=bv.z; Bs[lk+3][lr]=bv.w;
        __syncthreads();
        #pragma unroll
        for (int kk = 0; kk < 16; ++kk) {
            const float4 a4 = *(const float4*)&As[kk][ty*4];
            const float4 b4 = *(const float4*)&Bs[kk][tx*4];
            const float a[4] = {a4.x,a4.y,a4.z,a4.w};
            const float b[4] = {b4.x,b4.y,b4.z,b4.w};
            #pragma unroll
            for (int i = 0; i < 4; ++i)
                #pragma unroll
                for (int j = 0; j < 4; ++j)
                    acc[i][j] = fmaf(a[i], b[j], acc[i][j]);
        }
        __syncthreads();
    }
    #pragma unroll
    for (int i = 0; i < 4; ++i) {
        const int m = bm + ty*4 + i;
        float4 o;
        o.x = acc[i][0] + bias[bn+tx*4+0];
        o.y = acc[i][1] + bias[bn+tx*4+1];
        o.z = acc[i][2] + bias[bn+tx*4+2];
        o.w = acc[i][3] + bias[bn+tx*4+3];
        *(float4*)(out + (size_t)m * HID + bn + tx*4) = o;
    }
}

// ---------------------------------------------------------------------------
// Row sum-of-squares; head-batched via blockIdx.z (0 in fallback mode).
// ---------------------------------------------------------------------------
__global__ __launch_bounds__(64) void rownorm_kernel(
    const float* __restrict__ q, const float* __restrict__ k,
    float* __restrict__ sqq, float* __restrict__ sqk)
{
    const int row = blockIdx.x;
    const int hz  = blockIdx.z;
    const int lane = threadIdx.x;
    const float* src = (blockIdx.y ? k : q) + ((size_t)hz * NN + row) * HID;
    float4 v = *(const float4*)(src + lane * 4);
    float s = v.x*v.x + v.y*v.y + v.z*v.z + v.w*v.w;
    for (int off = 32; off; off >>= 1) s += __shfl_down(s, off);
    if (lane == 0) (blockIdx.y ? sqk : sqq)[(size_t)hz * NN + row] = s;
}

// ---------------------------------------------------------------------------
// Gram GEMM (NT, K=HID) + distance epilogue. 64x64 proven config.
// ---------------------------------------------------------------------------
__global__ __launch_bounds__(256) void dist_kernel(
    const float* __restrict__ q, const float* __restrict__ k,
    const float* __restrict__ sqq, const float* __restrict__ sqk,
    float* __restrict__ Dm)
{
    const int bm = blockIdx.x * 64;
    const int bn = blockIdx.y * 64;
    const int t  = threadIdx.x;
    const int tx = t & 15, ty = t >> 4;
    const int lr = t >> 2, lk = (t & 3) * 4;

    __shared__ float As[16][68];
    __shared__ float Bs[16][68];
    float acc[4][4] = {};

    for (int k0 = 0; k0 < HID; k0 += 16) {
        float4 av = *(const float4*)(q + (size_t)(bm + lr) * HID + k0 + lk);
        float4 bv = *(const float4*)(k + (size_t)(bn + lr) * HID + k0 + lk);
        As[lk+0][lr]=av.x; As[lk+1][lr]=av.y; As[lk+2][lr]=av.z; As[lk+3][lr]=av.w;
        Bs[lk+0][lr]=bv.x; Bs[lk+1][lr]=bv.y; Bs[lk+2][lr]=bv.z; Bs[lk+3][lr]=bv.w;
        __syncthreads();
        #pragma unroll
        for (int kk = 0; kk < 16; ++kk) {
            const float4 a4 = *(const float4*)&As[kk][ty*4];
            const float4 b4 = *(const float4*)&Bs[kk][tx*4];
            const float a[4] = {a4.x,a4.y,a4.z,a4.w};
            const float b[4] = {b4.x,b4.y,b4.z,b4.w};
            #pragma unroll
            for (int i = 0; i < 4; ++i)
                #pragma unroll
                for (int j = 0; j < 4; ++j)
                    acc[i][j] = fmaf(a[i], b[j], acc[i][j]);
        }
        __syncthreads();
    }
    #pragma unroll
    for (int i = 0; i < 4; ++i) {
        const int m = bm + ty*4 + i;
        const float sm = sqq[m];
        float4 o;
        float v0 = sm + sqk[bn+tx*4+0] - 2.0f*acc[i][0];
        float v1 = sm + sqk[bn+tx*4+1] - 2.0f*acc[i][1];
        float v2 = sm + sqk[bn+tx*4+2] - 2.0f*acc[i][2];
        float v3 = sm + sqk[bn+tx*4+3] - 2.0f*acc[i][3];
        o.x = sqrtf(fmaxf(v0, 0.0f) + 1e-10f);
        o.y = sqrtf(fmaxf(v1, 0.0f) + 1e-10f);
        o.z = sqrtf(fmaxf(v2, 0.0f) + 1e-10f);
        o.w = sqrtf(fmaxf(v3, 0.0f) + 1e-10f);
        *(float4*)(Dm + (size_t)m * NN + bn + tx*4) = o;
    }
}

// ---------------------------------------------------------------------------
// Per-row order stats: 11th and 30th smallest via register-resident radix
// bisection + ballot counting (no LDS; bit-identical ranks).
// ---------------------------------------------------------------------------
__device__ __forceinline__ unsigned kth_reg(const unsigned (&r)[64], int K)
{
    unsigned lo = 0u, hi = 0xFFFFFFFFu;
    while (lo < hi) {
        unsigned mid = lo + ((hi - lo) >> 1);
        int c = 0;
        #pragma unroll
        for (int i = 0; i < 64; ++i)
            c += (int)__popcll(__ballot(r[i] <= mid));
        if (c >= K) hi = mid; else lo = mid + 1;
    }
    return lo;
}

__global__ __launch_bounds__(64) void select_kernel(
    const float* __restrict__ Dm, float* __restrict__ mdp, float* __restrict__ kth)
{
    const int row = blockIdx.x;
    const int lane = threadIdx.x;
    const float* src = Dm + (size_t)row * NN + lane * 64;  // per-lane contiguous 256B
    unsigned r[64];
    #pragma unroll
    for (int c = 0; c < 16; ++c) {
        float4 v = *(const float4*)(src + c * 4);
        r[c*4+0] = __float_as_uint(v.x);
        r[c*4+1] = __float_as_uint(v.y);
        r[c*4+2] = __float_as_uint(v.z);
        r[c*4+3] = __float_as_uint(v.w);
    }
    unsigned v11 = kth_reg(r, 11);   // sort(d)[10]
    unsigned v30 = kth_reg(r, 30);   // sort(d)[29]
    if (lane == 0) {
        float md = __uint_as_float(v11) + 1e-10f;
        float t  = __uint_as_float(v30) / md;
        mdp[row] = md;
        kth[row] = expf(-(t*t));   // same expr as affsym -> identical rounding
    }
}

// ---------------------------------------------------------------------------
// FUSED affinity + symmetrize: A := aff(D) + aff(D)^T in one pass (round 10:
// one 128MB pass and 8 launches eliminated; bit-identical A). Block 0 also
// zeroes ovf_cnt (stream order: affsym completes before stats_extract).
// ---------------------------------------------------------------------------
__device__ __forceinline__ void aff4(float4& v, float m, float kt, bool diagtile,
                                     int r, int lc4)
{
    float t0 = v.x / m, t1 = v.y / m, t2 = v.z / m, t3 = v.w / m;
    float a0 = expf(-(t0*t0)), a1 = expf(-(t1*t1)), a2 = expf(-(t2*t2)), a3 = expf(-(t3*t3));
    a0 = (a0 >= kt) ? a0 : 0.0f;
    a1 = (a1 >= kt) ? a1 : 0.0f;
    a2 = (a2 >= kt) ? a2 : 0.0f;
    a3 = (a3 >= kt) ? a3 : 0.0f;
    if (diagtile) {
        if (lc4+0 == r) a0 = 1.0f;
        if (lc4+1 == r) a1 = 1.0f;
        if (lc4+2 == r) a2 = 1.0f;
        if (lc4+3 == r) a3 = 1.0f;
    }
    v.x = a0; v.y = a1; v.z = a2; v.w = a3;
}

__global__ __launch_bounds__(256) void affsym_kernel(
    float* __restrict__ Dm, const float* __restrict__ mdp, const float* __restrict__ kthv,
    int* __restrict__ ovf_cnt)
{
    if (blockIdx.x == 0 && threadIdx.x == 0) *ovf_cnt = 0;

    int rem = blockIdx.x;
    int bi = 0;
    while (rem >= 64 - bi) { rem -= 64 - bi; ++bi; }
    const int bj = bi + rem;
    const bool diagtile = (bi == bj);

    __shared__ float T1[64][65];
    __shared__ float T2[64][65];
    const int t = threadIdx.x;
    const int lr = t >> 4;
    const int lc4 = (t & 15) * 4;

    #pragma unroll
    for (int rr = 0; rr < 4; ++rr) {
        const int r = rr*16 + lr;
        {
            const int grow = bi*64 + r;
            const float m  = mdp[grow];
            const float kt = kthv[grow];
            float4 v1 = *(const float4*)(Dm + (size_t)grow * NN + bj*64 + lc4);
            aff4(v1, m, kt, diagtile, r, lc4);
            T1[r][lc4+0]=v1.x; T1[r][lc4+1]=v1.y; T1[r][lc4+2]=v1.z; T1[r][lc4+3]=v1.w;
        }
        {
            const int grow = bj*64 + r;
            const float m  = mdp[grow];
            const float kt = kthv[grow];
            float4 v2 = *(const float4*)(Dm + (size_t)grow * NN + bi*64 + lc4);
            aff4(v2, m, kt, diagtile, r, lc4);
            T2[r][lc4+0]=v2.x; T2[r][lc4+1]=v2.y; T2[r][lc4+2]=v2.z; T2[r][lc4+3]=v2.w;
        }
    }
    __syncthreads();
    #pragma unroll
    for (int rr = 0; rr < 4; ++rr) {
        const int r = rr*16 + lr;
        float4 o1;
        o1.x = T1[r][lc4+0] + T2[lc4+0][r];
        o1.y = T1[r][lc4+1] + T2[lc4+1][r];
        o1.z = T1[r][lc4+2] + T2[lc4+2][r];
        o1.w = T1[r][lc4+3] + T2[lc4+3][r];
        *(float4*)(Dm + (size_t)(bi*64 + r) * NN + bj*64 + lc4) = o1;
        if (!diagtile) {
            float4 o2;
            o2.x = T2[r][lc4+0] + T1[lc4+0][r];
            o2.y = T2[r][lc4+1] + T1[lc4+1][r];
            o2.z = T2[r][lc4+2] + T1[lc4+2][r];
            o2.w = T2[r][lc4+3] + T1[lc4+3][r];
            *(float4*)(Dm + (size_t)(bj*64 + r) * NN + bi*64 + lc4) = o2;
        }
    }
}

// ---------------------------------------------------------------------------
// Softmax row stats + sparse extraction. P[i][j] = ci + v_ij (v=0 off-support).
// Rows padded to a multiple of 8 with (col=0,val=0) so spmm can run fixed
// unroll-8 chunks. Entries beyond CAP spill to overflow list (exactness).
// ---------------------------------------------------------------------------
__global__ __launch_bounds__(256) void stats_extract_kernel(
    const float* __restrict__ A, float* __restrict__ cvec, int* __restrict__ nnz,
    int* __restrict__ cols, float* __restrict__ vals,
    int* __restrict__ ovf_cnt, int* __restrict__ ovf_row,
    int* __restrict__ ovf_col, float* __restrict__ ovf_val)
{
    __shared__ float srow[NN];
    __shared__ float red[8];
    __shared__ int cnt;
    const int row = blockIdx.x, t = threadIdx.x;
    const int lane = t & 63, wid = t >> 6;
    const float* src = A + (size_t)row * NN;

    float mx = -1e30f;
    #pragma unroll
    for (int c = 0; c < 4; ++c) {
        const int base = c*1024 + t*4;
        float4 v = *(const float4*)(src + base);
        *(float4*)&srow[base] = v;
        mx = fmaxf(mx, fmaxf(fmaxf(v.x, v.y), fmaxf(v.z, v.w)));
    }
    for (int off = 32; off; off >>= 1) mx = fmaxf(mx, __shfl_xor(mx, off));
    if (lane == 0) red[wid] = mx;
    __syncthreads();
    mx = fmaxf(fmaxf(red[0], red[1]), fmaxf(red[2], red[3]));

    float sum = 0.0f;
    #pragma unroll
    for (int c = 0; c < 4; ++c) {
        const int base = c*1024 + t*4;
        float4 v = *(float4*)&srow[base];
        sum += expf(v.x-mx) + expf(v.y-mx) + expf(v.z-mx) + expf(v.w-mx);
    }
    for (int off = 32; off; off >>= 1) sum += __shfl_xor(sum, off);
    if (lane == 0) red[4 + wid] = sum;
    if (t == 0) cnt = 0;
    __syncthreads();
    sum = red[4] + red[5] + red[6] + red[7];
    const float ci = expf(-mx) / sum;
    if (t == 0) cvec[row] = ci;

    for (int c = 0; c < 16; ++c) {
        const int j = c*256 + t;
        const float a = srow[j];
        if (a != 0.0f) {
            const float v = expf(a - mx)/sum - ci;
            int p = atomicAdd(&cnt, 1);
            if (p < CAP) {
                cols[(size_t)row*CAP + p] = j;
                vals[(size_t)row*CAP + p] = v;
            } else {
                int q = atomicAdd(ovf_cnt, 1);
                if (q < OVF_CAP) {
                    ovf_row[q] = row;
                    ovf_col[q] = j;
                    ovf_val[q] = v;
                }
            }
        }
    }
    __syncthreads();
    if (t == 0) {
        const int c2 = min(cnt, CAP);
        const int e2 = min((c2 + 7) & ~7, CAP);   // pad to multiple of 8
        for (int p = c2; p < e2; ++p) {
            cols[(size_t)row*CAP + p] = 0;
            vals[(size_t)row*CAP + p] = 0.0f;     // weight-0 gather of row 0: no-op
        }
        nnz[row] = e2 == c2 ? c2 : e2;            // padded count (multiple of 8)
    }
}

// ---------------------------------------------------------------------------
// Column sums of Y [NN][DIN], two-stage deterministic. (Round 11's fused
// atomic colsum and round 12's in-epilogue ovf scan BOTH regressed spmm
// 7x -- keep colsum and fixup as separate kernels; the launch overhead is
// the insurance premium.)
// ---------------------------------------------------------------------------
__global__ __launch_bounds__(256) void colsum_partial_kernel(
    const float* __restrict__ Y, float* __restrict__ part)
{
    const int cc = blockIdx.y * 256 + threadIdx.x;
    const int r0 = blockIdx.x * 128;
    float s = 0.0f;
    for (int r = 0; r < 128; ++r) s += Y[(size_t)(r0 + r) * DIN + cc];
    part[(size_t)blockIdx.x * DIN + cc] = s;
}

__global__ __launch_bounds__(256) void colsum_final_kernel(
    const float* __restrict__ part, float* __restrict__ colsum)
{
    const int cc = blockIdx.x * 256 + threadIdx.x;
    float s = 0.0f;
    #pragma unroll
    for (int r = 0; r < 32; ++r) s += part[(size_t)r * DIN + cc];
    colsum[cc] = s;
}

// ---------------------------------------------------------------------------
// Panel-blocked sparse+rank-1 application, XCD-pinned panels, float4 gathers
// (two sparse entries per VMEM instruction; round-9 best form, VERBATIM).
// Rounds 2/5/6/9 bracket this as the L2-line-service floor of the gather
// structure (~11.4 TB/s aggregate). Rounds 11/12 proved the epilogue must
// stay branch-free: ANY runtime-bound loop after the gather loop (even one
// that never executes) breaks the compiler's vmcnt staircase -> 7x slower.
// Do not add code between the gather loop and the store.
// mode 0: write; mode 1: write 0.25x; mode 2: += 0.25x
// ---------------------------------------------------------------------------
typedef float vf4 __attribute__((ext_vector_type(4)));

#define SPMM_LOAD(buf, b)                                               \
    _Pragma("unroll")                                                   \
    for (int u = 0; u < 4; ++u) {                                       \
        const int j = half ? rc[(b) + 2*u + 1] : rc[(b) + 2*u];         \
        buf[u] = *(const float4*)(Y + (size_t)j * DIN + cq);            \
    }

#define SPMM_FMA(buf, b)                                                \
    _Pragma("unroll")                                                   \
    for (int u = 0; u < 4; ++u) {                                       \
        const float v = half ? rv[(b) + 2*u + 1] : rv[(b) + 2*u];       \
        ax = fmaf(v, buf[u].x, ax);                                     \
        ay = fmaf(v, buf[u].y, ay);                                     \
        az = fmaf(v, buf[u].z, az);                                     \
        aw = fmaf(v, buf[u].w, aw);                                     \
    }

__global__ __launch_bounds__(256) void spmm_kernel(
    const float* __restrict__ Y, const float* __restrict__ colsum,
    const float* __restrict__ cvec, const int* __restrict__ nnz,
    const int* __restrict__ cols, const float* __restrict__ vals,
    float* __restrict__ Yout, int mode)
{
    const int wave = threadIdx.x >> 6, lane = threadIdx.x & 63;
    const int half = lane >> 5;             // half-wave: even/odd entry stream
    const int qc   = (lane & 31) * 4;       // col-block within panel (float4)

    // XCD-affinity swizzle: same XCD -> same panel for a long stretch.
    const int id     = blockIdx.x;          // 0 .. 16383
    const int xcd    = id & 7;
    const int w      = id >> 3;             // 0 .. 2047 within this XCD
    const int panel  = xcd + ((w & 1024) ? 8 : 0);   // 16 panels of PW cols
    const int rowblk = w & 1023;            // 0 .. 1023 (4 rows each)

    const int row = __builtin_amdgcn_readfirstlane(rowblk * 4 + wave);
    const int cq  = panel * PW + qc;

    const int n = nnz[row];               // multiple of 8 (padded), scalar
    const float ci = cvec[row];
    const int*   rc = cols + (size_t)row * CAP;   // SGPR base -> s_load
    const float* rv = vals + (size_t)row * CAP;

    const float4 s = *(const float4*)(colsum + cq);
    // rank-1 term counted once (half 0 only); halves summed at the end.
    float ax = half ? 0.0f : ci * s.x;
    float ay = half ? 0.0f : ci * s.y;
    float az = half ? 0.0f : ci * s.z;
    float aw = half ? 0.0f : ci * s.w;

    float4 yA[4], yB[4];
    SPMM_LOAD(yA, 0);
    int base = 8;
    bool tailA = true;
    while (base < n) {
        SPMM_LOAD(yB, base);
        SPMM_FMA(yA, base - 8);
        base += 8;
        if (base < n) {
            SPMM_LOAD(yA, base);
            SPMM_FMA(yB, base - 8);
            base += 8;
        } else {
            SPMM_FMA(yB, base - 8);
            tailA = false;
            break;
        }
    }
    if (tailA) { SPMM_FMA(yA, base - 8); }

    // combine half-wave partials (lane l <-> l+32 hold the same col-block)
    ax += __shfl_xor(ax, 32);
    ay += __shfl_xor(ay, 32);
    az += __shfl_xor(az, 32);
    aw += __shfl_xor(aw, 32);

    if (half == 0) {
        float* dst = Yout + (size_t)row * DIN + cq;
        vf4 o;
        if (mode == 0)      { o[0] = ax;       o[1] = ay;       o[2] = az;       o[3] = aw; }
        else if (mode == 1) { o[0] = 0.25f*ax; o[1] = 0.25f*ay; o[2] = 0.25f*az; o[3] = 0.25f*aw; }
        else {
            const vf4 p = __builtin_nontemporal_load((const vf4*)dst);
            o[0] = p[0] + 0.25f*ax; o[1] = p[1] + 0.25f*ay;
            o[2] = p[2] + 0.25f*az; o[3] = p[3] + 0.25f*aw;
        }
        __builtin_nontemporal_store(o, (vf4*)dst);
    }
}

// ---------------------------------------------------------------------------
// Apply spilled overflow entries: Yout[i][:] += scale * v * Y[j][:].
// Expected count ~0; exactness guarantee for hub rows with nnz > CAP.
// Kept as a SEPARATE kernel: folding this scan into spmm's epilogue cost 7x
// (rounds 11/12) even with cnt==0, by perturbing the gather-loop codegen.
// ---------------------------------------------------------------------------
__global__ __launch_bounds__(256) void spmm_fixup_kernel(
    const float* __restrict__ Y, const int* __restrict__ ovf_cnt,
    const int* __restrict__ ovf_row, const int* __restrict__ ovf_col,
    const float* __restrict__ ovf_val, float* __restrict__ Yout, float scale)
{
    const int cnt = min(*ovf_cnt, OVF_CAP);
    const int t = threadIdx.x;
    for (int e = blockIdx.x; e < cnt; e += gridDim.x) {
        const int i = ovf_row[e], j = ovf_col[e];
        const float v = ovf_val[e] * scale;
        const float* yr = Y + (size_t)j * DIN;
        float* dst = Yout + (size_t)i * DIN;
        #pragma unroll
        for (int c = t*4; c < DIN; c += 1024) {
            atomicAdd(dst + c + 0, v * yr[c + 0]);
            atomicAdd(dst + c + 1, v * yr[c + 1]);
            atomicAdd(dst + c + 2, v * yr[c + 2]);
            atomicAdd(dst + c + 3, v * yr[c + 3]);
        }
    }
}

// ---------------------------------------------------------------------------
extern "C" void kernel_launch(void* const* d_in, const int* in_sizes, int n_in,
                              void* d_out, int out_size, void* d_ws, size_t ws_size,
                              hipStream_t stream)
{
    const float* X  = (const float*)d_in[0];
    const float* Wq = (const float*)d_in[1];
    const float* bq = (const float*)d_in[2];
    const float* Wk = (const float*)d_in[3];
    const float* bk = (const float*)d_in[4];
    float* out = (float*)d_out;

    // Batched layout needs 4-head q/k buffers (+24MB vs fallback). Guarded by
    // ws_size; fallback is the proven per-head path.
    const size_t nf_batched = 8ull*NN*HID + (size_t)NN*NN + 2ull*(size_t)NN*CAP
                            + 32ull*DIN + 2ull*DIN + 8ull*NN /*sqq,sqk*/
                            + 3ull*NN /*mdp,kth,cvec*/ + (size_t)NN /*nnz*/
                            + 16 + 3ull*OVF_CAP;
    const bool batched = ws_size >= nf_batched * sizeof(float);
    const int nhq = batched ? NHEADS : 1;   // heads resident in q/k buffers

    float* ws    = (float*)d_ws;
    float* qbufs = ws;                                      // nhq*NN*HID
    float* kbufs = qbufs + (size_t)nhq*NN*HID;              // nhq*NN*HID
    float* A     = kbufs + (size_t)nhq*NN*HID;              // NN*NN (64MB)
    float* Y1    = A;                                       // overlays A
    float* Y2    = A + (size_t)NN*DIN;                      // overlays A upper half
    float* valsA = A + (size_t)NN*NN;                       // NN*CAP
    int*   colsA = (int*)(valsA + (size_t)NN*CAP);          // NN*CAP
    float* part  = (float*)(colsA + (size_t)NN*CAP);        // 32*DIN
    float* colsumX = part + 32*DIN;                         // DIN (colsum of X, head-invariant)
    float* colsumB = colsumX + DIN;                         // DIN (per-iteration colsum)
    float* sqq  = colsumB + DIN;                            // nhq*NN
    float* sqk  = sqq + (size_t)nhq*NN;                     // nhq*NN
    float* mdp  = sqk + (size_t)nhq*NN;
    float* kth  = mdp + NN;
    float* cvec = kth + NN;
    int*   nnz  = (int*)(cvec + NN);
    int*   ovf_cnt = nnz + NN;
    int*   ovf_row = ovf_cnt + 16;
    int*   ovf_col = ovf_row + OVF_CAP;
    float* ovf_val = (float*)(ovf_col + OVF_CAP);

    if (batched) {
        // All 4 heads x {q,k} in one launch: 2048 blocks (8/CU) vs 4x512.
        proj_kernel<<<dim3(NN/64, HID/64, 2*NHEADS), 256, 0, stream>>>(
            X, Wq, bq, Wk, bk, qbufs, kbufs, 0);
        rownorm_kernel<<<dim3(NN, 2, NHEADS), 64, 0, stream>>>(qbufs, kbufs, sqq, sqk);
    }
    // colsum(X) is head-invariant (tpow=1 src is always X): compute once.
    colsum_partial_kernel<<<dim3(32, DIN/256), 256, 0, stream>>>(X, part);
    colsum_final_kernel<<<dim3(DIN/256), 256, 0, stream>>>(part, colsumX);

    for (int h = 0; h < NHEADS; ++h) {
        if (!batched) {
            proj_kernel<<<dim3(NN/64, HID/64, 2), 256, 0, stream>>>(
                X, Wq, bq, Wk, bk, qbufs, kbufs, h);
            rownorm_kernel<<<dim3(NN, 2, 1), 64, 0, stream>>>(qbufs, kbufs, sqq, sqk);
        }
        const size_t ho = batched ? (size_t)h : 0;
        const float* qh   = qbufs + ho * NN * HID;
        const float* kh   = kbufs + ho * NN * HID;
        const float* sqqh = sqq + ho * NN;
        const float* sqkh = sqk + ho * NN;

        dist_kernel<<<dim3(NN/64, NN/64), 256, 0, stream>>>(qh, kh, sqqh, sqkh, A);
        select_kernel<<<dim3(NN), 64, 0, stream>>>(A, mdp, kth);
        affsym_kernel<<<dim3(2080), 256, 0, stream>>>(A, mdp, kth, ovf_cnt);
        stats_extract_kernel<<<dim3(NN), 256, 0, stream>>>(A, cvec, nnz, colsA, valsA,
                                                           ovf_cnt, ovf_row, ovf_col, ovf_val);

        const float* src = X;
        for (int tpow = 1; tpow <= 6; ++tpow) {
            const float* cs;
            if (tpow == 1) {
                cs = colsumX;   // precomputed, head-invariant
            } else {
                colsum_partial_kernel<<<dim3(32, DIN/256), 256, 0, stream>>>(src, part);
                colsum_final_kernel<<<dim3(DIN/256), 256, 0, stream>>>(part, colsumB);
                cs = colsumB;
            }
            float* dst;
            int mode;
            if (tpow == 6)      { dst = out; mode = (h == 0) ? 1 : 2; }
            else if (tpow & 1)  { dst = Y1;  mode = 0; }
            else                { dst = Y2;  mode = 0; }
            spmm_kernel<<<dim3((NN/4) * (DIN/PW)), 256, 0, stream>>>(
                src, cs, cvec, nnz, colsA, valsA, dst, mode);
            spmm_fixup_kernel<<<dim3(64), 256, 0, stream>>>(src, ovf_cnt, ovf_row, ovf_col, ovf_val,
                                                            dst, (tpow == 6) ? 0.25f : 1.0f);
            src = dst;
        }
    }
}

// Round 14
// 6069.302 us; speedup vs baseline: 2.6956x; 1.0136x over previous
//
#include <hip/hip_runtime.h>
#include <hip/hip_bf16.h>
#include <math.h>

#define NN 4096
#define DIN 2048
#define HID 256
#define NHEADS 4
#define CAP 1024       // fast-path nnz per row; multiple of 8 (padding invariant)
#define OVF_CAP 131072 // spill capacity for rows exceeding CAP (exactness guarantee)
#define PW 128         // spmm panel width (floats): 4096*PW*4B = 2MB panel -> fits one XCD L2

// ---------------------------------------------------------------------------
// Projection GEMM (NT): out[n][c] = sum_d X[n][d]*W[c][d] + b[c]
// 128x64 tile, 8x4 per thread (round 14): 32 FMA per 3 ds_read_b128 vs the
// old 64x64/4x4's 16:2 -- LDS pipe drops below VALU, barriers halve per FMA.
// Grid stays large (1024 blocks = 4/CU; round-7's 128-block starvation
// avoided). B-frag read is tx*4 (2-way bank alias = free); A-frag ty*8 is
// 16-lane broadcast. Ascending-K fmaf chain, identical pairing -> output
// bit-identical to the 64x64 kernel.
// Head-batched: blockIdx.z = head*2 + isK.
// ---------------------------------------------------------------------------
__global__ __launch_bounds__(256) void proj_kernel(
    const float* __restrict__ X, const float* __restrict__ Wq, const float* __restrict__ bq,
    const float* __restrict__ Wk, const float* __restrict__ bk,
    float* __restrict__ qb, float* __restrict__ kb, int h0)
{
    const int isK  = blockIdx.z & 1;
    const int hidx = blockIdx.z >> 1;        // head index within this launch
    const int hh   = h0 + hidx;              // weight head
    const float* W    = (isK ? Wk : Wq) + (size_t)hh * HID * DIN;
    const float* bias = (isK ? bk : bq) + hh * HID;
    float* out = (isK ? kb : qb) + (size_t)hidx * NN * HID;

    const int bm = blockIdx.x * 128;
    const int bn = blockIdx.y * 64;
    const int t  = threadIdx.x;
    const int tx = t & 15, ty = t >> 4;     // tx: 4-col group, ty: 8-row group
    const int ar = t >> 1;                  // A staging row 0..127
    const int ac = (t & 1) * 8;             // A staging col {0,8}
    const int br = t >> 2;                  // B staging row 0..63
    const int bc = (t & 3) * 4;             // B staging col {0,4,8,12}

    __shared__ float As[16][132];
    __shared__ float Bs[16][68];
    float acc[8][4] = {};

    for (int k0 = 0; k0 < DIN; k0 += 16) {
        const float4 a0 = *(const float4*)(X + (size_t)(bm + ar) * DIN + k0 + ac);
        const float4 a1 = *(const float4*)(X + (size_t)(bm + ar) * DIN + k0 + ac + 4);
        const float4 b0 = *(const float4*)(W + (size_t)(bn + br) * DIN + k0 + bc);
        As[ac+0][ar]=a0.x; As[ac+1][ar]=a0.y; As[ac+2][ar]=a0.z; As[ac+3][ar]=a0.w;
        As[ac+4][ar]=a1.x; As[ac+5][ar]=a1.y; As[ac+6][ar]=a1.z; As[ac+7][ar]=a1.w;
        Bs[bc+0][br]=b0.x; Bs[bc+1][br]=b0.y; Bs[bc+2][br]=b0.z; Bs[bc+3][br]=b0.w;
        __syncthreads();
        #pragma unroll
        for (int kk = 0; kk < 16; ++kk) {
            const float4 aa0 = *(const float4*)&As[kk][ty*8];
            const float4 aa1 = *(const float4*)&As[kk][ty*8+4];
            const float4 b4  = *(const float4*)&Bs[kk][tx*4];
            const float a[8] = {aa0.x,aa0.y,aa0.z,aa0.w,aa1.x,aa1.y,aa1.z,aa1.w};
            const float b[4] = {b4.x,b4.y,b4.z,b4.w};
            #pragma unroll
            for (int i = 0; i < 8; ++i)
                #pragma unroll
                for (int j = 0; j < 4; ++j)
                    acc[i][j] = fmaf(a[i], b[j], acc[i][j]);
        }
        __syncthreads();
    }
    #pragma unroll
    for (int i = 0; i < 8; ++i) {
        const int m = bm + ty*8 + i;
        float4 o;
        o.x = acc[i][0] + bias[bn+tx*4+0];
        o.y = acc[i][1] + bias[bn+tx*4+1];
        o.z = acc[i][2] + bias[bn+tx*4+2];
        o.w = acc[i][3] + bias[bn+tx*4+3];
        *(float4*)(out + (size_t)m * HID + bn + tx*4) = o;
    }
}

// ---------------------------------------------------------------------------
// Row sum-of-squares; head-batched via blockIdx.z (0 in fallback mode).
// ---------------------------------------------------------------------------
__global__ __launch_bounds__(64) void rownorm_kernel(
    const float* __restrict__ q, const float* __restrict__ k,
    float* __restrict__ sqq, float* __restrict__ sqk)
{
    const int row = blockIdx.x;
    const int hz  = blockIdx.z;
    const int lane = threadIdx.x;
    const float* src = (blockIdx.y ? k : q) + ((size_t)hz * NN + row) * HID;
    float4 v = *(const float4*)(src + lane * 4);
    float s = v.x*v.x + v.y*v.y + v.z*v.z + v.w*v.w;
    for (int off = 32; off; off >>= 1) s += __shfl_down(s, off);
    if (lane == 0) (blockIdx.y ? sqk : sqq)[(size_t)hz * NN + row] = s;
}

// ---------------------------------------------------------------------------
// Gram GEMM (NT, K=HID) + distance epilogue. 128x64 tile, 8x4 per thread
// (same structure and bit-exactness argument as proj_kernel). Grid 32x64 =
// 2048 blocks = 8/CU.
// ---------------------------------------------------------------------------
__global__ __launch_bounds__(256) void dist_kernel(
    const float* __restrict__ q, const float* __restrict__ k,
    const float* __restrict__ sqq, const float* __restrict__ sqk,
    float* __restrict__ Dm)
{
    const int bm = blockIdx.x * 128;
    const int bn = blockIdx.y * 64;
    const int t  = threadIdx.x;
    const int tx = t & 15, ty = t >> 4;
    const int ar = t >> 1;                  // A staging row 0..127
    const int ac = (t & 1) * 8;             // A staging col {0,8}
    const int br = t >> 2;                  // B staging row 0..63
    const int bc = (t & 3) * 4;             // B staging col {0,4,8,12}

    __shared__ float As[16][132];
    __shared__ float Bs[16][68];
    float acc[8][4] = {};

    for (int k0 = 0; k0 < HID; k0 += 16) {
        const float4 a0 = *(const float4*)(q + (size_t)(bm + ar) * HID + k0 + ac);
        const float4 a1 = *(const float4*)(q + (size_t)(bm + ar) * HID + k0 + ac + 4);
        const float4 b0 = *(const float4*)(k + (size_t)(bn + br) * HID + k0 + bc);
        As[ac+0][ar]=a0.x; As[ac+1][ar]=a0.y; As[ac+2][ar]=a0.z; As[ac+3][ar]=a0.w;
        As[ac+4][ar]=a1.x; As[ac+5][ar]=a1.y; As[ac+6][ar]=a1.z; As[ac+7][ar]=a1.w;
        Bs[bc+0][br]=b0.x; Bs[bc+1][br]=b0.y; Bs[bc+2][br]=b0.z; Bs[bc+3][br]=b0.w;
        __syncthreads();
        #pragma unroll
        for (int kk = 0; kk < 16; ++kk) {
            const float4 aa0 = *(const float4*)&As[kk][ty*8];
            const float4 aa1 = *(const float4*)&As[kk][ty*8+4];
            const float4 b4  = *(const float4*)&Bs[kk][tx*4];
            const float a[8] = {aa0.x,aa0.y,aa0.z,aa0.w,aa1.x,aa1.y,aa1.z,aa1.w};
            const float b[4] = {b4.x,b4.y,b4.z,b4.w};
            #pragma unroll
            for (int i = 0; i < 8; ++i)
                #pragma unroll
                for (int j = 0; j < 4; ++j)
                    acc[i][j] = fmaf(a[i], b[j], acc[i][j]);
        }
        __syncthreads();
    }
    #pragma unroll
    for (int i = 0; i < 8; ++i) {
        const int m = bm + ty*8 + i;
        const float sm = sqq[m];
        float4 o;
        float v0 = sm + sqk[bn+tx*4+0] - 2.0f*acc[i][0];
        float v1 = sm + sqk[bn+tx*4+1] - 2.0f*acc[i][1];
        float v2 = sm + sqk[bn+tx*4+2] - 2.0f*acc[i][2];
        float v3 = sm + sqk[bn+tx*4+3] - 2.0f*acc[i][3];
        o.x = sqrtf(fmaxf(v0, 0.0f) + 1e-10f);
        o.y = sqrtf(fmaxf(v1, 0.0f) + 1e-10f);
        o.z = sqrtf(fmaxf(v2, 0.0f) + 1e-10f);
        o.w = sqrtf(fmaxf(v3, 0.0f) + 1e-10f);
        *(float4*)(Dm + (size_t)m * NN + bn + tx*4) = o;
    }
}

// ---------------------------------------------------------------------------
// Per-row order stats: 11th and 30th smallest via register-resident radix
// bisection + ballot counting (no LDS; bit-identical ranks).
// ---------------------------------------------------------------------------
__device__ __forceinline__ unsigned kth_reg(const unsigned (&r)[64], int K)
{
    unsigned lo = 0u, hi = 0xFFFFFFFFu;
    while (lo < hi) {
        unsigned mid = lo + ((hi - lo) >> 1);
        int c = 0;
        #pragma unroll
        for (int i = 0; i < 64; ++i)
            c += (int)__popcll(__ballot(r[i] <= mid));
        if (c >= K) hi = mid; else lo = mid + 1;
    }
    return lo;
}

__global__ __launch_bounds__(64) void select_kernel(
    const float* __restrict__ Dm, float* __restrict__ mdp, float* __restrict__ kth)
{
    const int row = blockIdx.x;
    const int lane = threadIdx.x;
    const float* src = Dm + (size_t)row * NN + lane * 64;  // per-lane contiguous 256B
    unsigned r[64];
    #pragma unroll
    for (int c = 0; c < 16; ++c) {
        float4 v = *(const float4*)(src + c * 4);
        r[c*4+0] = __float_as_uint(v.x);
        r[c*4+1] = __float_as_uint(v.y);
        r[c*4+2] = __float_as_uint(v.z);
        r[c*4+3] = __float_as_uint(v.w);
    }
    unsigned v11 = kth_reg(r, 11);   // sort(d)[10]
    unsigned v30 = kth_reg(r, 30);   // sort(d)[29]
    if (lane == 0) {
        float md = __uint_as_float(v11) + 1e-10f;
        float t  = __uint_as_float(v30) / md;
        mdp[row] = md;
        kth[row] = expf(-(t*t));   // same expr as affsym -> identical rounding
    }
}

// ---------------------------------------------------------------------------
// FUSED affinity + symmetrize: A := aff(D) + aff(D)^T in one pass (round 10:
// one 128MB pass and 8 launches eliminated; bit-identical A). Block 0 also
// zeroes ovf_cnt (stream order: affsym completes before stats_extract).
// ---------------------------------------------------------------------------
__device__ __forceinline__ void aff4(float4& v, float m, float kt, bool diagtile,
                                     int r, int lc4)
{
    float t0 = v.x / m, t1 = v.y / m, t2 = v.z / m, t3 = v.w / m;
    float a0 = expf(-(t0*t0)), a1 = expf(-(t1*t1)), a2 = expf(-(t2*t2)), a3 = expf(-(t3*t3));
    a0 = (a0 >= kt) ? a0 : 0.0f;
    a1 = (a1 >= kt) ? a1 : 0.0f;
    a2 = (a2 >= kt) ? a2 : 0.0f;
    a3 = (a3 >= kt) ? a3 : 0.0f;
    if (diagtile) {
        if (lc4+0 == r) a0 = 1.0f;
        if (lc4+1 == r) a1 = 1.0f;
        if (lc4+2 == r) a2 = 1.0f;
        if (lc4+3 == r) a3 = 1.0f;
    }
    v.x = a0; v.y = a1; v.z = a2; v.w = a3;
}

__global__ __launch_bounds__(256) void affsym_kernel(
    float* __restrict__ Dm, const float* __restrict__ mdp, const float* __restrict__ kthv,
    int* __restrict__ ovf_cnt)
{
    if (blockIdx.x == 0 && threadIdx.x == 0) *ovf_cnt = 0;

    int rem = blockIdx.x;
    int bi = 0;
    while (rem >= 64 - bi) { rem -= 64 - bi; ++bi; }
    const int bj = bi + rem;
    const bool diagtile = (bi == bj);

    __shared__ float T1[64][65];
    __shared__ float T2[64][65];
    const int t = threadIdx.x;
    const int lr = t >> 4;
    const int lc4 = (t & 15) * 4;

    #pragma unroll
    for (int rr = 0; rr < 4; ++rr) {
        const int r = rr*16 + lr;
        {
            const int grow = bi*64 + r;
            const float m  = mdp[grow];
            const float kt = kthv[grow];
            float4 v1 = *(const float4*)(Dm + (size_t)grow * NN + bj*64 + lc4);
            aff4(v1, m, kt, diagtile, r, lc4);
            T1[r][lc4+0]=v1.x; T1[r][lc4+1]=v1.y; T1[r][lc4+2]=v1.z; T1[r][lc4+3]=v1.w;
        }
        {
            const int grow = bj*64 + r;
            const float m  = mdp[grow];
            const float kt = kthv[grow];
            float4 v2 = *(const float4*)(Dm + (size_t)grow * NN + bi*64 + lc4);
            aff4(v2, m, kt, diagtile, r, lc4);
            T2[r][lc4+0]=v2.x; T2[r][lc4+1]=v2.y; T2[r][lc4+2]=v2.z; T2[r][lc4+3]=v2.w;
        }
    }
    __syncthreads();
    #pragma unroll
    for (int rr = 0; rr < 4; ++rr) {
        const int r = rr*16 + lr;
        float4 o1;
        o1.x = T1[r][lc4+0] + T2[lc4+0][r];
        o1.y = T1[r][lc4+1] + T2[lc4+1][r];
        o1.z = T1[r][lc4+2] + T2[lc4+2][r];
        o1.w = T1[r][lc4+3] + T2[lc4+3][r];
        *(float4*)(Dm + (size_t)(bi*64 + r) * NN + bj*64 + lc4) = o1;
        if (!diagtile) {
            float4 o2;
            o2.x = T2[r][lc4+0] + T1[lc4+0][r];
            o2.y = T2[r][lc4+1] + T1[lc4+1][r];
            o2.z = T2[r][lc4+2] + T1[lc4+2][r];
            o2.w = T2[r][lc4+3] + T1[lc4+3][r];
            *(float4*)(Dm + (size_t)(bj*64 + r) * NN + bi*64 + lc4) = o2;
        }
    }
}

// ---------------------------------------------------------------------------
// Softmax row stats + sparse extraction. P[i][j] = ci + v_ij (v=0 off-support).
// Rows padded to a multiple of 8 with (col=0,val=0) so spmm can run fixed
// unroll-8 chunks. Entries beyond CAP spill to overflow list (exactness).
// ---------------------------------------------------------------------------
__global__ __launch_bounds__(256) void stats_extract_kernel(
    const float* __restrict__ A, float* __restrict__ cvec, int* __restrict__ nnz,
    int* __restrict__ cols, float* __restrict__ vals,
    int* __restrict__ ovf_cnt, int* __restrict__ ovf_row,
    int* __restrict__ ovf_col, float* __restrict__ ovf_val)
{
    __shared__ float srow[NN];
    __shared__ float red[8];
    __shared__ int cnt;
    const int row = blockIdx.x, t = threadIdx.x;
    const int lane = t & 63, wid = t >> 6;
    const float* src = A + (size_t)row * NN;

    float mx = -1e30f;
    #pragma unroll
    for (int c = 0; c < 4; ++c) {
        const int base = c*1024 + t*4;
        float4 v = *(const float4*)(src + base);
        *(float4*)&srow[base] = v;
        mx = fmaxf(mx, fmaxf(fmaxf(v.x, v.y), fmaxf(v.z, v.w)));
    }
    for (int off = 32; off; off >>= 1) mx = fmaxf(mx, __shfl_xor(mx, off));
    if (lane == 0) red[wid] = mx;
    __syncthreads();
    mx = fmaxf(fmaxf(red[0], red[1]), fmaxf(red[2], red[3]));

    float sum = 0.0f;
    #pragma unroll
    for (int c = 0; c < 4; ++c) {
        const int base = c*1024 + t*4;
        float4 v = *(float4*)&srow[base];
        sum += expf(v.x-mx) + expf(v.y-mx) + expf(v.z-mx) + expf(v.w-mx);
    }
    for (int off = 32; off; off >>= 1) sum += __shfl_xor(sum, off);
    if (lane == 0) red[4 + wid] = sum;
    if (t == 0) cnt = 0;
    __syncthreads();
    sum = red[4] + red[5] + red[6] + red[7];
    const float ci = expf(-mx) / sum;
    if (t == 0) cvec[row] = ci;

    for (int c = 0; c < 16; ++c) {
        const int j = c*256 + t;
        const float a = srow[j];
        if (a != 0.0f) {
            const float v = expf(a - mx)/sum - ci;
            int p = atomicAdd(&cnt, 1);
            if (p < CAP) {
                cols[(size_t)row*CAP + p] = j;
                vals[(size_t)row*CAP + p] = v;
            } else {
                int q = atomicAdd(ovf_cnt, 1);
                if (q < OVF_CAP) {
                    ovf_row[q] = row;
                    ovf_col[q] = j;
                    ovf_val[q] = v;
                }
            }
        }
    }
    __syncthreads();
    if (t == 0) {
        const int c2 = min(cnt, CAP);
        const int e2 = min((c2 + 7) & ~7, CAP);   // pad to multiple of 8
        for (int p = c2; p < e2; ++p) {
            cols[(size_t)row*CAP + p] = 0;
            vals[(size_t)row*CAP + p] = 0.0f;     // weight-0 gather of row 0: no-op
        }
        nnz[row] = e2 == c2 ? c2 : e2;            // padded count (multiple of 8)
    }
}

// ---------------------------------------------------------------------------
// Column sums of Y [NN][DIN], two-stage deterministic. (Round 11's fused
// atomic colsum and round 12's in-epilogue ovf scan BOTH regressed spmm
// 7x -- keep colsum and fixup as separate kernels; the launch overhead is
// the insurance premium.)
// ---------------------------------------------------------------------------
__global__ __launch_bounds__(256) void colsum_partial_kernel(
    const float* __restrict__ Y, float* __restrict__ part)
{
    const int cc = blockIdx.y * 256 + threadIdx.x;
    const int r0 = blockIdx.x * 128;
    float s = 0.0f;
    for (int r = 0; r < 128; ++r) s += Y[(size_t)(r0 + r) * DIN + cc];
    part[(size_t)blockIdx.x * DIN + cc] = s;
}

__global__ __launch_bounds__(256) void colsum_final_kernel(
    const float* __restrict__ part, float* __restrict__ colsum)
{
    const int cc = blockIdx.x * 256 + threadIdx.x;
    float s = 0.0f;
    #pragma unroll
    for (int r = 0; r < 32; ++r) s += part[(size_t)r * DIN + cc];
    colsum[cc] = s;
}

// ---------------------------------------------------------------------------
// Panel-blocked sparse+rank-1 application, XCD-pinned panels, float4 gathers
// (two sparse entries per VMEM instruction; round-9 best form, VERBATIM).
// Rounds 2/5/6/9 bracket this as the L2-line-service floor of the gather
// structure (~11.4 TB/s aggregate). Rounds 11/12 proved the epilogue must
// stay branch-free: ANY runtime-bound loop after the gather loop (even one
// that never executes) breaks the compiler's vmcnt staircase -> 7x slower.
// Do not add code between the gather loop and the store.
// mode 0: write; mode 1: write 0.25x; mode 2: += 0.25x
// ---------------------------------------------------------------------------
typedef float vf4 __attribute__((ext_vector_type(4)));

#define SPMM_LOAD(buf, b)                                               \
    _Pragma("unroll")                                                   \
    for (int u = 0; u < 4; ++u) {                                       \
        const int j = half ? rc[(b) + 2*u + 1] : rc[(b) + 2*u];         \
        buf[u] = *(const float4*)(Y + (size_t)j * DIN + cq);            \
    }

#define SPMM_FMA(buf, b)                                                \
    _Pragma("unroll")                                                   \
    for (int u = 0; u < 4; ++u) {                                       \
        const float v = half ? rv[(b) + 2*u + 1] : rv[(b) + 2*u];       \
        ax = fmaf(v, buf[u].x, ax);                                     \
        ay = fmaf(v, buf[u].y, ay);                                     \
        az = fmaf(v, buf[u].z, az);                                     \
        aw = fmaf(v, buf[u].w, aw);                                     \
    }

__global__ __launch_bounds__(256) void spmm_kernel(
    const float* __restrict__ Y, const float* __restrict__ colsum,
    const float* __restrict__ cvec, const int* __restrict__ nnz,
    const int* __restrict__ cols, const float* __restrict__ vals,
    float* __restrict__ Yout, int mode)
{
    const int wave = threadIdx.x >> 6, lane = threadIdx.x & 63;
    const int half = lane >> 5;             // half-wave: even/odd entry stream
    const int qc   = (lane & 31) * 4;       // col-block within panel (float4)

    // XCD-affinity swizzle: same XCD -> same panel for a long stretch.
    const int id     = blockIdx.x;          // 0 .. 16383
    const int xcd    = id & 7;
    const int w      = id >> 3;             // 0 .. 2047 within this XCD
    const int panel  = xcd + ((w & 1024) ? 8 : 0);   // 16 panels of PW cols
    const int rowblk = w & 1023;            // 0 .. 1023 (4 rows each)

    const int row = __builtin_amdgcn_readfirstlane(rowblk * 4 + wave);
    const int cq  = panel * PW + qc;

    const int n = nnz[row];               // multiple of 8 (padded), scalar
    const float ci = cvec[row];
    const int*   rc = cols + (size_t)row * CAP;   // SGPR base -> s_load
    const float* rv = vals + (size_t)row * CAP;

    const float4 s = *(const float4*)(colsum + cq);
    // rank-1 term counted once (half 0 only); halves summed at the end.
    float ax = half ? 0.0f : ci * s.x;
    float ay = half ? 0.0f : ci * s.y;
    float az = half ? 0.0f : ci * s.z;
    float aw = half ? 0.0f : ci * s.w;

    float4 yA[4], yB[4];
    SPMM_LOAD(yA, 0);
    int base = 8;
    bool tailA = true;
    while (base < n) {
        SPMM_LOAD(yB, base);
        SPMM_FMA(yA, base - 8);
        base += 8;
        if (base < n) {
            SPMM_LOAD(yA, base);
            SPMM_FMA(yB, base - 8);
            base += 8;
        } else {
            SPMM_FMA(yB, base - 8);
            tailA = false;
            break;
        }
    }
    if (tailA) { SPMM_FMA(yA, base - 8); }

    // combine half-wave partials (lane l <-> l+32 hold the same col-block)
    ax += __shfl_xor(ax, 32);
    ay += __shfl_xor(ay, 32);
    az += __shfl_xor(az, 32);
    aw += __shfl_xor(aw, 32);

    if (half == 0) {
        float* dst = Yout + (size_t)row * DIN + cq;
        vf4 o;
        if (mode == 0)      { o[0] = ax;       o[1] = ay;       o[2] = az;       o[3] = aw; }
        else if (mode == 1) { o[0] = 0.25f*ax; o[1] = 0.25f*ay; o[2] = 0.25f*az; o[3] = 0.25f*aw; }
        else {
            const vf4 p = __builtin_nontemporal_load((const vf4*)dst);
            o[0] = p[0] + 0.25f*ax; o[1] = p[1] + 0.25f*ay;
            o[2] = p[2] + 0.25f*az; o[3] = p[3] + 0.25f*aw;
        }
        __builtin_nontemporal_store(o, (vf4*)dst);
    }
}

// ---------------------------------------------------------------------------
// Apply spilled overflow entries: Yout[i][:] += scale * v * Y[j][:].
// Expected count ~0; exactness guarantee for hub rows with nnz > CAP.
// Kept as a SEPARATE kernel: folding this scan into spmm's epilogue cost 7x
// (rounds 11/12) even with cnt==0, by perturbing the gather-loop codegen.
// ---------------------------------------------------------------------------
__global__ __launch_bounds__(256) void spmm_fixup_kernel(
    const float* __restrict__ Y, const int* __restrict__ ovf_cnt,
    const int* __restrict__ ovf_row, const int* __restrict__ ovf_col,
    const float* __restrict__ ovf_val, float* __restrict__ Yout, float scale)
{
    const int cnt = min(*ovf_cnt, OVF_CAP);
    const int t = threadIdx.x;
    for (int e = blockIdx.x; e < cnt; e += gridDim.x) {
        const int i = ovf_row[e], j = ovf_col[e];
        const float v = ovf_val[e] * scale;
        const float* yr = Y + (size_t)j * DIN;
        float* dst = Yout + (size_t)i * DIN;
        #pragma unroll
        for (int c = t*4; c < DIN; c += 1024) {
            atomicAdd(dst + c + 0, v * yr[c + 0]);
            atomicAdd(dst + c + 1, v * yr[c + 1]);
            atomicAdd(dst + c + 2, v * yr[c + 2]);
            atomicAdd(dst + c + 3, v * yr[c + 3]);
        }
    }
}

// ---------------------------------------------------------------------------
extern "C" void kernel_launch(void* const* d_in, const int* in_sizes, int n_in,
                              void* d_out, int out_size, void* d_ws, size_t ws_size,
                              hipStream_t stream)
{
    const float* X  = (const float*)d_in[0];
    const float* Wq = (const float*)d_in[1];
    const float* bq = (const float*)d_in[2];
    const float* Wk = (const float*)d_in[3];
    const float* bk = (const float*)d_in[4];
    float* out = (float*)d_out;

    // Batched layout needs 4-head q/k buffers (+24MB vs fallback). Guarded by
    // ws_size; fallback is the proven per-head path.
    const size_t nf_batched = 8ull*NN*HID + (size_t)NN*NN + 2ull*(size_t)NN*CAP
                            + 32ull*DIN + 2ull*DIN + 8ull*NN /*sqq,sqk*/
                            + 3ull*NN /*mdp,kth,cvec*/ + (size_t)NN /*nnz*/
                            + 16 + 3ull*OVF_CAP;
    const bool batched = ws_size >= nf_batched * sizeof(float);
    const int nhq = batched ? NHEADS : 1;   // heads resident in q/k buffers

    float* ws    = (float*)d_ws;
    float* qbufs = ws;                                      // nhq*NN*HID
    float* kbufs = qbufs + (size_t)nhq*NN*HID;              // nhq*NN*HID
    float* A     = kbufs + (size_t)nhq*NN*HID;              // NN*NN (64MB)
    float* Y1    = A;                                       // overlays A
    float* Y2    = A + (size_t)NN*DIN;                      // overlays A upper half
    float* valsA = A + (size_t)NN*NN;                       // NN*CAP
    int*   colsA = (int*)(valsA + (size_t)NN*CAP);          // NN*CAP
    float* part  = (float*)(colsA + (size_t)NN*CAP);        // 32*DIN
    float* colsumX = part + 32*DIN;                         // DIN (colsum of X, head-invariant)
    float* colsumB = colsumX + DIN;                         // DIN (per-iteration colsum)
    float* sqq  = colsumB + DIN;                            // nhq*NN
    float* sqk  = sqq + (size_t)nhq*NN;                     // nhq*NN
    float* mdp  = sqk + (size_t)nhq*NN;
    float* kth  = mdp + NN;
    float* cvec = kth + NN;
    int*   nnz  = (int*)(cvec + NN);
    int*   ovf_cnt = nnz + NN;
    int*   ovf_row = ovf_cnt + 16;
    int*   ovf_col = ovf_row + OVF_CAP;
    float* ovf_val = (float*)(ovf_col + OVF_CAP);

    if (batched) {
        // All 4 heads x {q,k} in one launch: 1024 blocks (4/CU).
        proj_kernel<<<dim3(NN/128, HID/64, 2*NHEADS), 256, 0, stream>>>(
            X, Wq, bq, Wk, bk, qbufs, kbufs, 0);
        rownorm_kernel<<<dim3(NN, 2, NHEADS), 64, 0, stream>>>(qbufs, kbufs, sqq, sqk);
    }
    // colsum(X) is head-invariant (tpow=1 src is always X): compute once.
    colsum_partial_kernel<<<dim3(32, DIN/256), 256, 0, stream>>>(X, part);
    colsum_final_kernel<<<dim3(DIN/256), 256, 0, stream>>>(part, colsumX);

    for (int h = 0; h < NHEADS; ++h) {
        if (!batched) {
            proj_kernel<<<dim3(NN/128, HID/64, 2), 256, 0, stream>>>(
                X, Wq, bq, Wk, bk, qbufs, kbufs, h);
            rownorm_kernel<<<dim3(NN, 2, 1), 64, 0, stream>>>(qbufs, kbufs, sqq, sqk);
        }
        const size_t ho = batched ? (size_t)h : 0;
        const float* qh   = qbufs + ho * NN * HID;
        const float* kh   = kbufs + ho * NN * HID;
        const float* sqqh = sqq + ho * NN;
        const float* sqkh = sqk + ho * NN;

        dist_kernel<<<dim3(NN/128, NN/64), 256, 0, stream>>>(qh, kh, sqqh, sqkh, A);
        select_kernel<<<dim3(NN), 64, 0, stream>>>(A, mdp, kth);
        affsym_kernel<<<dim3(2080), 256, 0, stream>>>(A, mdp, kth, ovf_cnt);
        stats_extract_kernel<<<dim3(NN), 256, 0, stream>>>(A, cvec, nnz, colsA, valsA,
                                                           ovf_cnt, ovf_row, ovf_col, ovf_val);

        const float* src = X;
        for (int tpow = 1; tpow <= 6; ++tpow) {
            const float* cs;
            if (tpow == 1) {
                cs = colsumX;   // precomputed, head-invariant
            } else {
                colsum_partial_kernel<<<dim3(32, DIN/256), 256, 0, stream>>>(src, part);
                colsum_final_kernel<<<dim3(DIN/256), 256, 0, stream>>>(part, colsumB);
                cs = colsumB;
            }
            float* dst;
            int mode;
            if (tpow == 6)      { dst = out; mode = (h == 0) ? 1 : 2; }
            else if (tpow & 1)  { dst = Y1;  mode = 0; }
            else                { dst = Y2;  mode = 0; }
            spmm_kernel<<<dim3((NN/4) * (DIN/PW)), 256, 0, stream>>>(
                src, cs, cvec, nnz, colsA, valsA, dst, mode);
            spmm_fixup_kernel<<<dim3(64), 256, 0, stream>>>(src, ovf_cnt, ovf_row, ovf_col, ovf_val,
                                                            dst, (tpow == 6) ? 0.25f : 1.0f);
            src = dst;
        }
    }
}